// Round 3
// baseline (307.511 us; speedup 1.0000x reference)
//
#include <hip/hip_runtime.h>

// Problem constants
#define NPIX   32768      // B*H*W
#define NEMB_  8192
#define EMB_   64
#define CH_    128
#define SPLIT  8          // code chunks (1024 codes each)
#define CT_PER 32         // code-tiles (of 32) per chunk

// d_out layout (float elements)
#define OUT_OFF  0
#define ZQ_OFF   2097152
#define LOSS_OFF 4194304
#define IND_OFF  4194305

typedef _Float16 h8   __attribute__((ext_vector_type(8)));
typedef float    f16f __attribute__((ext_vector_type(16)));

// ---------------------------------------------------------------------------
// K1: 1x1 conv projection (split-K over 2 threads/pixel) + xsq + X-fragment pack.
// X' K-layout per pixel (80 slots): [0,64)=fp16(x); 64,65=-0.5; rest 0.
// Fragment order: X4[(t*5+s)*64 + lane], pixel n=32t+(lane&31), k=16s+8(lane>>5)+j
__global__ __launch_bounds__(256) void k_proj_prep(
    const float* __restrict__ z, const float* __restrict__ pw,
    const float* __restrict__ pb, float* __restrict__ z_e,
    float* __restrict__ xsq, float4* __restrict__ X4)
{
    __shared__ __align__(16) float wT[CH_ * EMB_];   // [c][e] 32KB
    __shared__ __align__(16) float zf[128 * EMB_];   // [px][e] 32KB
    const int tid  = threadIdx.x;
    const int pxl  = tid & 127;
    const int half = tid >> 7;
    for (int i = tid; i < CH_ * EMB_; i += 256) {
        int c = i >> 6, e = i & 63;
        wT[i] = pw[e * CH_ + c];
    }
    __syncthreads();

    const int n  = blockIdx.x * 128 + pxl;
    const int b  = n >> 10;
    const int hw = n & 1023;
    const float* zp = z + (size_t)b * (CH_ * 1024) + (size_t)(half * 64) * 1024 + hw;

    float acc[EMB_];
    #pragma unroll
    for (int i = 0; i < EMB_; i++) acc[i] = 0.f;
    for (int c = 0; c < 64; c++) {
        float zv = zp[(size_t)c * 1024];
        const float4* w4 = (const float4*)(wT + (half * 64 + c) * EMB_);
        #pragma unroll
        for (int i = 0; i < 16; i++) {
            float4 v = w4[i];
            acc[4*i]   = fmaf(zv, v.x, acc[4*i]);
            acc[4*i+1] = fmaf(zv, v.y, acc[4*i+1]);
            acc[4*i+2] = fmaf(zv, v.z, acc[4*i+2]);
            acc[4*i+3] = fmaf(zv, v.w, acc[4*i+3]);
        }
    }
    float4* d = (float4*)(zf + pxl * EMB_);
    if (half == 1) {
        #pragma unroll
        for (int i = 0; i < 16; i++)
            d[i] = make_float4(acc[4*i], acc[4*i+1], acc[4*i+2], acc[4*i+3]);
    }
    __syncthreads();
    if (half == 0) {
        const float4* bb = (const float4*)pb;
        float4* zo = (float4*)(z_e + (size_t)n * EMB_);
        float s = 0.f;
        #pragma unroll
        for (int i = 0; i < 16; i++) {
            float4 v = d[i];
            float4 bv = bb[i];
            v.x += acc[4*i]   + bv.x;
            v.y += acc[4*i+1] + bv.y;
            v.z += acc[4*i+2] + bv.z;
            v.w += acc[4*i+3] + bv.w;
            d[i] = v;
            zo[i] = v;
            s += v.x*v.x + v.y*v.y + v.z*v.z + v.w*v.w;
        }
        xsq[n] = s;
    }
    __syncthreads();
    // fragment pack (both halves write their own k-range)
    const int t  = n >> 5;
    const int li = n & 31;
    #pragma unroll
    for (int s5 = 0; s5 < 5; s5++) {
        h8 hh;
        if (s5 < 4) {
            #pragma unroll
            for (int j = 0; j < 8; j++)
                hh[j] = (_Float16)zf[pxl * EMB_ + s5 * 16 + half * 8 + j];
        } else {
            #pragma unroll
            for (int j = 0; j < 8; j++) hh[j] = (_Float16)0.f;
            if (half == 0) { hh[0] = (_Float16)-0.5f; hh[1] = (_Float16)-0.5f; }
        }
        X4[(size_t)(t * 5 + s5) * 64 + half * 32 + li] = __builtin_bit_cast(float4, hh);
    }
}

// ---------------------------------------------------------------------------
// K1b: wsq, W-fragment pack (K=80: wh + wsq hi/lo), per-block max(wsq), zero counters.
__global__ __launch_bounds__(256) void k_wprep(
    const float* __restrict__ ew, float* __restrict__ wsq,
    float* __restrict__ wsqp, float4* __restrict__ W4,
    int* __restrict__ cnt, float* __restrict__ lacc)
{
    const int tid = threadIdx.x;
    const int m   = blockIdx.x * 256 + tid;
    const float4* wr = (const float4*)(ew + (size_t)m * EMB_);
    float w[EMB_];
    float s = 0.f;
    #pragma unroll
    for (int i = 0; i < 16; i++) {
        float4 v = wr[i];
        w[4*i] = v.x; w[4*i+1] = v.y; w[4*i+2] = v.z; w[4*i+3] = v.w;
        s += v.x*v.x + v.y*v.y + v.z*v.z + v.w*v.w;
    }
    wsq[m] = s;
    float sh = (float)(_Float16)s;
    float sl = s - sh;
    const int t  = m >> 5;
    const int li = m & 31;
    #pragma unroll
    for (int s5 = 0; s5 < 4; s5++) {
        #pragma unroll
        for (int h = 0; h < 2; h++) {
            h8 hh;
            #pragma unroll
            for (int j = 0; j < 8; j++) hh[j] = (_Float16)w[s5 * 16 + h * 8 + j];
            W4[(size_t)(t * 5 + s5) * 64 + h * 32 + li] = __builtin_bit_cast(float4, hh);
        }
    }
    {   // s5 = 4: slots 64=s_hi, 65=s_lo, rest 0
        h8 hh;
        #pragma unroll
        for (int j = 0; j < 8; j++) hh[j] = (_Float16)0.f;
        hh[0] = (_Float16)sh; hh[1] = (_Float16)sl;
        W4[(size_t)(t * 5 + 4) * 64 + 0 * 32 + li] = __builtin_bit_cast(float4, hh);
        #pragma unroll
        for (int j = 0; j < 8; j++) hh[j] = (_Float16)0.f;
        W4[(size_t)(t * 5 + 4) * 64 + 1 * 32 + li] = __builtin_bit_cast(float4, hh);
    }
    __shared__ float red[256];
    red[tid] = s;
    __syncthreads();
    for (int o = 128; o > 0; o >>= 1) {
        if (tid < o) red[tid] = fmaxf(red[tid], red[tid + o]);
        __syncthreads();
    }
    if (tid == 0) wsqp[blockIdx.x] = red[0];
    if (blockIdx.x == 0 && tid == 0) { *cnt = 0; *lacc = 0.f; }
}

// ---------------------------------------------------------------------------
// K2: coarse MFMA pass. acc = xh.wh - wsq/2 (maximize). 4 B-tiles/wave.
// Exact streaming top-2 value + packed index. grid (64, SPLIT), block 256.
__global__ __launch_bounds__(256, 2) void k_pass1(
    const float4* __restrict__ X4, const float4* __restrict__ W4,
    float* __restrict__ pm1, int* __restrict__ pi1, float* __restrict__ pm2)
{
    const int lane  = threadIdx.x & 63;
    const int wv    = threadIdx.x >> 6;
    const int chunk = blockIdx.y;
    const int pt0   = blockIdx.x * 16 + wv * 4;

    h8 bfr[4][5];
    #pragma unroll
    for (int j = 0; j < 4; j++)
        #pragma unroll
        for (int s = 0; s < 5; s++)
            bfr[j][s] = __builtin_bit_cast(h8, X4[(size_t)((pt0 + j) * 5 + s) * 64 + lane]);

    float m1[4], m2[4];
    int   ip[4];
    #pragma unroll
    for (int j = 0; j < 4; j++) { m1[j] = -3.0e38f; m2[j] = -3.0e38f; ip[j] = 0; }

    const f16f zero16 = {0,0,0,0,0,0,0,0,0,0,0,0,0,0,0,0};

    for (int tt = 0; tt < CT_PER; tt++) {
        const int gt = chunk * CT_PER + tt;
        const float4* wp = W4 + (size_t)gt * 320 + lane;
        float4 a4[5];
        #pragma unroll
        for (int s = 0; s < 5; s++) a4[s] = wp[s * 64];

        f16f acc[4];
        #pragma unroll
        for (int j = 0; j < 4; j++) acc[j] = zero16;
        #pragma unroll
        for (int s = 0; s < 5; s++) {
            h8 a = __builtin_bit_cast(h8, a4[s]);
            #pragma unroll
            for (int j = 0; j < 4; j++)
                acc[j] = __builtin_amdgcn_mfma_f32_32x32x16_f16(a, bfr[j][s], acc[j], 0, 0, 0);
        }
        #pragma unroll
        for (int j = 0; j < 4; j++) {
            #pragma unroll
            for (int r = 0; r < 16; r++) {
                float v  = acc[j][r];
                int   pk = (tt << 4) | r;          // uniform -> SGPR cndmask src
                float tmn = fminf(m1[j], v);
                m2[j] = fmaxf(m2[j], tmn);
                bool  g = v > m1[j];
                ip[j] = g ? pk : ip[j];
                m1[j] = fmaxf(m1[j], v);
            }
        }
    }

    #pragma unroll
    for (int j = 0; j < 4; j++) {
        const int ipj = ip[j];
        int row = ((ipj >> 4) << 5) + (ipj & 3) + ((ipj >> 2) & 3) * 8 + ((lane >> 5) << 2);
        int gidx = chunk * 1024 + row;
        float om1 = __shfl_xor(m1[j], 32);
        float om2 = __shfl_xor(m2[j], 32);
        int   og  = __shfl_xor(gidx, 32);
        float nm2 = fmaxf(fmaxf(m2[j], om2), fminf(m1[j], om1));
        if (om1 > m1[j] || (om1 == m1[j] && og < gidx)) { m1[j] = om1; gidx = og; }
        if (lane < 32) {
            const int px = (pt0 + j) * 32 + lane;
            pm1[(size_t)chunk * NPIX + px] = m1[j];
            pi1[(size_t)chunk * NPIX + px] = gidx;
            pm2[(size_t)chunk * NPIX + px] = nm2;
        }
    }
}

// ---------------------------------------------------------------------------
// K3: combine chunks; certify with error bound; finalize certain pixels inline;
// queue uncertain pixels for exact fallback.
__global__ __launch_bounds__(256) void k_combine(
    const float* __restrict__ pm1, const int* __restrict__ pi1,
    const float* __restrict__ pm2, const float* __restrict__ xsq,
    const float* __restrict__ wsqp, const float* __restrict__ ew,
    float* __restrict__ out, float* __restrict__ lacc,
    int* __restrict__ cnt, int* __restrict__ flist)
{
    __shared__ float wmax_s;
    __shared__ float lred[256];
    const int tid = threadIdx.x;
    if (tid == 0) {
        float wm = wsqp[0];
        for (int k = 1; k < 32; k++) wm = fmaxf(wm, wsqp[k]);
        wmax_s = wm;
    }
    __syncthreads();
    const float wmax = wmax_s;

    const int n = blockIdx.x * 256 + tid;
    float bm = -3.0e38f, b2 = -3.0e38f;
    int   bi = 0;
    #pragma unroll
    for (int c = 0; c < SPLIT; c++) {
        float a1 = pm1[(size_t)c * NPIX + n];
        float a2 = pm2[(size_t)c * NPIX + n];
        int   ai = pi1[(size_t)c * NPIX + n];
        if (a1 > bm) { b2 = fmaxf(b2, fmaxf(bm, a2)); bm = a1; bi = ai; }
        else         { b2 = fmaxf(b2, a1); }
    }
    float S = sqrtf(xsq[n] * wmax);
    float E = 0.00125f * S + 1e-5f * wmax + 3e-4f;
    bool certain = (bm - b2) > 2.0f * E;

    float lsum = 0.f;
    if (certain) {
        const int b_  = n >> 10;
        const int hw  = n & 1023;
        const float4* wr = (const float4*)(ew + (size_t)bi * EMB_);
        float4* zr = (float4*)(out + ZQ_OFF + (size_t)n * EMB_);
        float* outp = out + OUT_OFF + (size_t)b_ * (EMB_ * 1024) + hw;
        #pragma unroll
        for (int i = 0; i < 16; i++) {
            float4 w4 = wr[i];
            float4 z4 = zr[i];
            float d0 = w4.x - z4.x, d1 = w4.y - z4.y;
            float d2 = w4.z - z4.z, d3 = w4.w - z4.w;
            lsum += d0*d0 + d1*d1 + d2*d2 + d3*d3;
            zr[i] = w4;
            outp[(4*i + 0) * 1024] = w4.x;
            outp[(4*i + 1) * 1024] = w4.y;
            outp[(4*i + 2) * 1024] = w4.z;
            outp[(4*i + 3) * 1024] = w4.w;
        }
        out[IND_OFF + n] = (float)bi;
    } else {
        int pos = atomicAdd(cnt, 1);
        flist[pos] = n;
    }
    lred[tid] = lsum;
    __syncthreads();
    for (int o = 128; o > 0; o >>= 1) {
        if (tid < o) lred[tid] += lred[tid + o];
        __syncthreads();
    }
    if (tid == 0) atomicAdd(lacc, lred[0]);
}

// ---------------------------------------------------------------------------
// K4: exact fp32 fallback for uncertain pixels. Block per pixel (grid-stride).
__global__ __launch_bounds__(256) void k_pass2(
    const int* __restrict__ flist, const int* __restrict__ cnt,
    const float* __restrict__ pm1, const int* __restrict__ pi1,
    const float* __restrict__ pm2, const float* __restrict__ xsq,
    const float* __restrict__ wsqp, const float* __restrict__ wsq,
    const float* __restrict__ ew, const float* __restrict__ z_e,
    float* __restrict__ out, float* __restrict__ lacc)
{
    __shared__ float xs[EMB_];
    __shared__ float sd[256];
    __shared__ int   sm[256];
    __shared__ float wmax_s;
    const int tid = threadIdx.x;
    if (tid == 0) {
        float wm = wsqp[0];
        for (int k = 1; k < 32; k++) wm = fmaxf(wm, wsqp[k]);
        wmax_s = wm;
    }
    __syncthreads();
    const float wmax = wmax_s;
    const int nf = *cnt;

    for (int f = blockIdx.x; f < nf; f += gridDim.x) {
        const int n = flist[f];
        if (tid < EMB_) xs[tid] = z_e[(size_t)n * EMB_ + tid];
        __syncthreads();

        // recompute coarse best + threshold (wider window than certification)
        float bm = -3.0e38f;
        #pragma unroll
        for (int c = 0; c < SPLIT; c++) bm = fmaxf(bm, pm1[(size_t)c * NPIX + n]);
        float S = sqrtf(xsq[n] * wmax);
        float E = 0.00125f * S + 1e-5f * wmax + 3e-4f;
        float thr = bm - 2.5f * E;

        float bestd = 3.0e38f;
        int   bestm = 0x7FFFFFFF;
        // full-chunk scans where even 2nd-best coarse is in-window
        for (int c = 0; c < SPLIT; c++) {
            if (pm2[(size_t)c * NPIX + n] >= thr) {
                for (int it = 0; it < 4; it++) {
                    const int m = c * 1024 + it * 256 + tid;
                    const float4* wr = (const float4*)(ew + (size_t)m * EMB_);
                    const float4* x4 = (const float4*)xs;
                    float dp = 0.f;
                    #pragma unroll
                    for (int i = 0; i < 16; i++) {
                        float4 wv = wr[i];
                        float4 xv = x4[i];
                        dp = fmaf(wv.x, xv.x, dp); dp = fmaf(wv.y, xv.y, dp);
                        dp = fmaf(wv.z, xv.z, dp); dp = fmaf(wv.w, xv.w, dp);
                    }
                    float dd = wsq[m] - 2.f * dp;
                    if (dd < bestd || (dd == bestd && m < bestm)) { bestd = dd; bestm = m; }
                }
            }
        }
        // per-chunk winner candidates
        if (tid < SPLIT) {
            const int c = tid;
            if (pm1[(size_t)c * NPIX + n] >= thr) {
                const int m = pi1[(size_t)c * NPIX + n];
                const float4* wr = (const float4*)(ew + (size_t)m * EMB_);
                const float4* x4 = (const float4*)xs;
                float dp = 0.f;
                #pragma unroll
                for (int i = 0; i < 16; i++) {
                    float4 wv = wr[i];
                    float4 xv = x4[i];
                    dp = fmaf(wv.x, xv.x, dp); dp = fmaf(wv.y, xv.y, dp);
                    dp = fmaf(wv.z, xv.z, dp); dp = fmaf(wv.w, xv.w, dp);
                }
                float dd = wsq[m] - 2.f * dp;
                if (dd < bestd || (dd == bestd && m < bestm)) { bestd = dd; bestm = m; }
            }
        }
        sd[tid] = bestd; sm[tid] = bestm;
        __syncthreads();
        for (int o = 128; o > 0; o >>= 1) {
            if (tid < o) {
                float d2 = sd[tid + o]; int mi = sm[tid + o];
                if (d2 < sd[tid] || (d2 == sd[tid] && mi < sm[tid])) { sd[tid] = d2; sm[tid] = mi; }
            }
            __syncthreads();
        }
        const int win = sm[0];

        if (tid < EMB_) {
            const int b_  = n >> 10;
            const int hw  = n & 1023;
            float wv = ew[(size_t)win * EMB_ + tid];
            float dx = wv - xs[tid];
            out[ZQ_OFF + (size_t)n * EMB_ + tid] = wv;
            out[OUT_OFF + (size_t)b_ * (EMB_ * 1024) + tid * 1024 + hw] = wv;
            float v = dx * dx;
            #pragma unroll
            for (int o = 32; o > 0; o >>= 1) v += __shfl_down(v, o);
            if (tid == 0) {
                atomicAdd(lacc, v);
                out[IND_OFF + n] = (float)win;
            }
        }
        __syncthreads();
    }
}

// ---------------------------------------------------------------------------
__global__ __launch_bounds__(64) void k_loss(
    const float* __restrict__ lacc, float* __restrict__ out)
{
    if (threadIdx.x == 0)
        out[LOSS_OFF] = 12.5f * (*lacc / 2097152.0f);
}

// ---------------------------------------------------------------------------
extern "C" void kernel_launch(void* const* d_in, const int* in_sizes, int n_in,
                              void* d_out, int out_size, void* d_ws, size_t ws_size,
                              hipStream_t stream)
{
    const float* z  = (const float*)d_in[0];
    const float* pw = (const float*)d_in[1];
    const float* pb = (const float*)d_in[2];
    const float* ew = (const float*)d_in[3];
    float* out = (float*)d_out;

    char* ws = (char*)d_ws;
    float4* X4   = (float4*)(ws);                      // 1024*5*64*16 = 5,242,880
    float4* W4   = (float4*)(ws + 5242880);            // 256*5*64*16  = 1,310,720
    float*  pm1  = (float*) (ws + 6553600);            // 1,048,576
    int*    pi1  = (int*)   (ws + 7602176);            // 1,048,576
    float*  pm2  = (float*) (ws + 8650752);            // 1,048,576
    float*  xsq  = (float*) (ws + 9699328);            //   131,072
    float*  wsq  = (float*) (ws + 9830400);            //    32,768
    float*  wsqp = (float*) (ws + 9863168);            //       128
    int*    flist= (int*)   (ws + 9863296);            //   131,072
    int*    cnt  = (int*)   (ws + 9994368);            //         4
    float*  lacc = (float*) (ws + 9994372);            //         4

    float* z_e = out + ZQ_OFF;   // z_q_flat region doubles as z_e scratch

    hipLaunchKernelGGL(k_proj_prep, dim3(256),       dim3(256), 0, stream, z, pw, pb, z_e, xsq, X4);
    hipLaunchKernelGGL(k_wprep,     dim3(32),        dim3(256), 0, stream, ew, wsq, wsqp, W4, cnt, lacc);
    hipLaunchKernelGGL(k_pass1,     dim3(64, SPLIT), dim3(256), 0, stream, X4, W4, pm1, pi1, pm2);
    hipLaunchKernelGGL(k_combine,   dim3(128),       dim3(256), 0, stream, pm1, pi1, pm2, xsq, wsqp, ew, out, lacc, cnt, flist);
    hipLaunchKernelGGL(k_pass2,     dim3(256),       dim3(256), 0, stream, flist, cnt, pm1, pi1, pm2, xsq, wsqp, wsq, ew, z_e, out, lacc);
    hipLaunchKernelGGL(k_loss,      dim3(1),         dim3(64),  0, stream, lacc, out);
}

// Round 4
// 233.326 us; speedup vs baseline: 1.3179x; 1.3179x over previous
//
#include <hip/hip_runtime.h>

// Problem constants
#define NPIX   32768      // B*H*W
#define NEMB_  8192
#define EMB_   64
#define CH_    128
#define NCHUNK 8          // code chunks (1024 codes = 32 tiles each)
#define CT_PER 32         // 32-code tiles per chunk

// d_out layout (float elements)
#define OUT_OFF  0
#define ZQ_OFF   2097152
#define LOSS_OFF 4194304
#define IND_OFF  4194305

typedef _Float16 h8   __attribute__((ext_vector_type(8)));
typedef float    f16f __attribute__((ext_vector_type(16)));

// ---------------------------------------------------------------------------
// K1 fused: blocks [0,256): 1x1-conv projection + xsq + X-fragment pack.
//           blocks [256,288): codebook wsq + W-fragment pack + wsqp + zero ctrs.
// X'/W' K-layout (80 slots): [0,64)=fp16(val); X slots 64,65=-0.5, W slots
// 64=wsq_hi,65=wsq_lo; rest 0.  Fragment order: F4[(t*5+s)*64 + lane],
// row m=32t+(lane&31), k=16s+8*(lane>>5)+j.
__global__ __launch_bounds__(256) void k_prep(
    const float* __restrict__ z, const float* __restrict__ pw,
    const float* __restrict__ pb, const float* __restrict__ ew,
    float* __restrict__ z_e, float* __restrict__ xsq,
    float4* __restrict__ X4, float4* __restrict__ W4,
    float* __restrict__ wsq, float* __restrict__ wsqp,
    float* __restrict__ lacc, int* __restrict__ done)
{
    const int tid = threadIdx.x;
    if (blockIdx.x >= 256) {
        // ---- codebook role ----
        const int m = (blockIdx.x - 256) * 256 + tid;
        const float4* wr = (const float4*)(ew + (size_t)m * EMB_);
        float w[EMB_];
        float s = 0.f;
        #pragma unroll
        for (int i = 0; i < 16; i++) {
            float4 v = wr[i];
            w[4*i] = v.x; w[4*i+1] = v.y; w[4*i+2] = v.z; w[4*i+3] = v.w;
            s += v.x*v.x + v.y*v.y + v.z*v.z + v.w*v.w;
        }
        wsq[m] = s;
        float sh = (float)(_Float16)s;
        float sl = s - sh;
        const int t  = m >> 5;
        const int li = m & 31;
        #pragma unroll
        for (int s5 = 0; s5 < 4; s5++) {
            #pragma unroll
            for (int h = 0; h < 2; h++) {
                h8 hh;
                #pragma unroll
                for (int j = 0; j < 8; j++) hh[j] = (_Float16)w[s5 * 16 + h * 8 + j];
                W4[(size_t)(t * 5 + s5) * 64 + h * 32 + li] = __builtin_bit_cast(float4, hh);
            }
        }
        {
            h8 hh;
            #pragma unroll
            for (int j = 0; j < 8; j++) hh[j] = (_Float16)0.f;
            hh[0] = (_Float16)sh; hh[1] = (_Float16)sl;
            W4[(size_t)(t * 5 + 4) * 64 + 0 * 32 + li] = __builtin_bit_cast(float4, hh);
            #pragma unroll
            for (int j = 0; j < 8; j++) hh[j] = (_Float16)0.f;
            W4[(size_t)(t * 5 + 4) * 64 + 1 * 32 + li] = __builtin_bit_cast(float4, hh);
        }
        __shared__ float red[256];
        red[tid] = s;
        __syncthreads();
        for (int o = 128; o > 0; o >>= 1) {
            if (tid < o) red[tid] = fmaxf(red[tid], red[tid + o]);
            __syncthreads();
        }
        if (tid == 0) wsqp[blockIdx.x - 256] = red[0];
        if (blockIdx.x == 256 && tid == 0) { *lacc = 0.f; *done = 0; }
        return;
    }
    // ---- projection role (split-K by 2) ----
    __shared__ __align__(16) float wT[CH_ * EMB_];
    __shared__ __align__(16) float zf[128 * EMB_];
    const int pxl  = tid & 127;
    const int half = tid >> 7;
    for (int i = tid; i < CH_ * EMB_; i += 256) {
        int c = i >> 6, e = i & 63;
        wT[i] = pw[e * CH_ + c];
    }
    __syncthreads();

    const int n  = blockIdx.x * 128 + pxl;
    const int b  = n >> 10;
    const int hw = n & 1023;
    const float* zp = z + (size_t)b * (CH_ * 1024) + (size_t)(half * 64) * 1024 + hw;

    float acc[EMB_];
    #pragma unroll
    for (int i = 0; i < EMB_; i++) acc[i] = 0.f;
    for (int c = 0; c < 64; c++) {
        float zv = zp[(size_t)c * 1024];
        const float4* w4 = (const float4*)(wT + (half * 64 + c) * EMB_);
        #pragma unroll
        for (int i = 0; i < 16; i++) {
            float4 v = w4[i];
            acc[4*i]   = fmaf(zv, v.x, acc[4*i]);
            acc[4*i+1] = fmaf(zv, v.y, acc[4*i+1]);
            acc[4*i+2] = fmaf(zv, v.z, acc[4*i+2]);
            acc[4*i+3] = fmaf(zv, v.w, acc[4*i+3]);
        }
    }
    float4* d = (float4*)(zf + pxl * EMB_);
    if (half == 1) {
        #pragma unroll
        for (int i = 0; i < 16; i++)
            d[i] = make_float4(acc[4*i], acc[4*i+1], acc[4*i+2], acc[4*i+3]);
    }
    __syncthreads();
    if (half == 0) {
        const float4* bb = (const float4*)pb;
        float4* zo = (float4*)(z_e + (size_t)n * EMB_);
        float s = 0.f;
        #pragma unroll
        for (int i = 0; i < 16; i++) {
            float4 v = d[i];
            float4 bv = bb[i];
            v.x += acc[4*i]   + bv.x;
            v.y += acc[4*i+1] + bv.y;
            v.z += acc[4*i+2] + bv.z;
            v.w += acc[4*i+3] + bv.w;
            d[i] = v;
            zo[i] = v;
            s += v.x*v.x + v.y*v.y + v.z*v.z + v.w*v.w;
        }
        xsq[n] = s;
    }
    __syncthreads();
    const int t  = n >> 5;
    const int li = n & 31;
    #pragma unroll
    for (int s5 = 0; s5 < 5; s5++) {
        h8 hh;
        if (s5 < 4) {
            #pragma unroll
            for (int j = 0; j < 8; j++)
                hh[j] = (_Float16)zf[pxl * EMB_ + s5 * 16 + half * 8 + j];
        } else {
            #pragma unroll
            for (int j = 0; j < 8; j++) hh[j] = (_Float16)0.f;
            if (half == 0) { hh[0] = (_Float16)-0.5f; hh[1] = (_Float16)-0.5f; }
        }
        X4[(size_t)(t * 5 + s5) * 64 + half * 32 + li] = __builtin_bit_cast(float4, hh);
    }
}

// ---------------------------------------------------------------------------
// K2: coarse MFMA pass, max-only epilogue -> per-chunk top-3 TILE maxima
// (+ tile indices for top-2) per pixel.  grid (64, NCHUNK), block 256.
__global__ __launch_bounds__(256, 2) void k_pass1(
    const float4* __restrict__ X4, const float4* __restrict__ W4,
    float* __restrict__ s1a, int* __restrict__ i1a,
    float* __restrict__ s2a, int* __restrict__ i2a,
    float* __restrict__ s3a)
{
    const int lane  = threadIdx.x & 63;
    const int wv    = threadIdx.x >> 6;
    const int chunk = blockIdx.y;
    const int pt0   = blockIdx.x * 16 + wv * 4;

    h8 bfr[4][5];
    #pragma unroll
    for (int j = 0; j < 4; j++)
        #pragma unroll
        for (int s = 0; s < 5; s++)
            bfr[j][s] = __builtin_bit_cast(h8, X4[(size_t)((pt0 + j) * 5 + s) * 64 + lane]);

    float s1[4], s2[4], s3[4];
    int   i1[4], i2[4];
    #pragma unroll
    for (int j = 0; j < 4; j++) {
        s1[j] = -3.0e38f; s2[j] = -3.0e38f; s3[j] = -3.0e38f;
        i1[j] = 0; i2[j] = 0;
    }

    const f16f zero16 = {0,0,0,0,0,0,0,0,0,0,0,0,0,0,0,0};

    for (int tt = 0; tt < CT_PER; tt++) {
        const int gt = chunk * CT_PER + tt;          // global tile id
        const float4* wp = W4 + (size_t)gt * 320 + lane;
        float4 a4[5];
        #pragma unroll
        for (int s = 0; s < 5; s++) a4[s] = wp[s * 64];

        f16f acc[4];
        #pragma unroll
        for (int j = 0; j < 4; j++) acc[j] = zero16;
        #pragma unroll
        for (int s = 0; s < 5; s++) {
            h8 a = __builtin_bit_cast(h8, a4[s]);
            #pragma unroll
            for (int j = 0; j < 4; j++)
                acc[j] = __builtin_amdgcn_mfma_f32_32x32x16_f16(a, bfr[j][s], acc[j], 0, 0, 0);
        }
        #pragma unroll
        for (int j = 0; j < 4; j++) {
            // 16-reg max tree (this lane's half of the pixel's 32 rows)
            float m0 = fmaxf(acc[j][0],  acc[j][1]);
            float m1 = fmaxf(acc[j][2],  acc[j][3]);
            float m2 = fmaxf(acc[j][4],  acc[j][5]);
            float m3 = fmaxf(acc[j][6],  acc[j][7]);
            float m4 = fmaxf(acc[j][8],  acc[j][9]);
            float m5 = fmaxf(acc[j][10], acc[j][11]);
            float m6 = fmaxf(acc[j][12], acc[j][13]);
            float m7 = fmaxf(acc[j][14], acc[j][15]);
            m0 = fmaxf(m0, m1); m2 = fmaxf(m2, m3);
            m4 = fmaxf(m4, m5); m6 = fmaxf(m6, m7);
            m0 = fmaxf(m0, m2); m4 = fmaxf(m4, m6);
            float v = fmaxf(m0, m4);
            v = fmaxf(v, __shfl_xor(v, 32));         // full 32-row tile max
            // top-3 tile update (identical in both lane halves)
            bool c1 = v > s1[j];
            bool c2 = v > s2[j];
            int  cand = c1 ? i1[j] : gt;
            i2[j] = c2 ? cand : i2[j];
            s3[j] = fmaxf(fminf(s2[j], v), s3[j]);   // med3(s2,s3,v)
            s3[j] = fminf(s3[j], fmaxf(s2[j], v));
            s2[j] = fmaxf(fminf(s1[j], v), fminf(s2[j], fmaxf(s1[j], v))); // med3
            i1[j] = c1 ? gt : i1[j];
            s1[j] = fmaxf(s1[j], v);
        }
    }

    if (lane < 32) {
        #pragma unroll
        for (int j = 0; j < 4; j++) {
            const int p = (pt0 + j) * 32 + lane;
            const size_t o = (size_t)chunk * NPIX + p;
            s1a[o] = s1[j]; i1a[o] = i1[j];
            s2a[o] = s2[j]; i2a[o] = i2[j];
            s3a[o] = s3[j];
        }
    }
}

// ---------------------------------------------------------------------------
// exact fp32 scan of one 32-code tile (wave-cooperative; 2 lanes per code)
__device__ __forceinline__ void scan_tile(
    int t, int lane, const float* __restrict__ ew, const float* __restrict__ wsq,
    const float x[32], float& bd, int& bm)
{
    const int m = t * 32 + (lane & 31);
    const float4* w4 = (const float4*)(ew + (size_t)m * EMB_ + ((lane >> 5) << 5));
    float dp = 0.f;
    #pragma unroll
    for (int i = 0; i < 8; i++) {
        float4 wv = w4[i];
        dp = fmaf(wv.x, x[4*i],   dp);
        dp = fmaf(wv.y, x[4*i+1], dp);
        dp = fmaf(wv.z, x[4*i+2], dp);
        dp = fmaf(wv.w, x[4*i+3], dp);
    }
    dp += __shfl_xor(dp, 32);                  // both halves: full 64-dim dot
    float d = fmaf(-2.f, dp, wsq[m]);
    if (d < bd || (d == bd && m < bm)) { bd = d; bm = m; }
}

// ---------------------------------------------------------------------------
// K3: per-pixel exact selection among certified candidate tiles.
// Wave per pixel; block 256 = 4 pixels; grid 8192.
__global__ __launch_bounds__(256) void k_select(
    const float* __restrict__ s1a, const int* __restrict__ i1a,
    const float* __restrict__ s2a, const int* __restrict__ i2a,
    const float* __restrict__ s3a, const float* __restrict__ xsq,
    const float* __restrict__ wsqp, const float* __restrict__ wsq,
    const float* __restrict__ ew, const float* __restrict__ z_e,
    int* __restrict__ fidx)
{
    const int lane = threadIdx.x & 63;
    const int wv   = threadIdx.x >> 6;
    const int n    = blockIdx.x * 4 + wv;

    float wm = wsqp[0];
    #pragma unroll
    for (int k = 1; k < 32; k++) wm = fmaxf(wm, wsqp[k]);

    float cs1[NCHUNK], cs2[NCHUNK], cs3[NCHUNK];
    int   ci1[NCHUNK], ci2[NCHUNK];
    float s1g = -3.0e38f;
    #pragma unroll
    for (int c = 0; c < NCHUNK; c++) {
        const size_t o = (size_t)c * NPIX + n;
        cs1[c] = s1a[o]; ci1[c] = i1a[o];
        cs2[c] = s2a[o]; ci2[c] = i2a[o];
        cs3[c] = s3a[o];
        s1g = fmaxf(s1g, cs1[c]);
    }
    const float E   = 0.00125f * sqrtf(xsq[n] * wm) + 1e-5f * wm + 3e-4f;
    const float thr = s1g - 2.0f * E;

    // this lane's 32-dim half of x, in registers
    float x[32];
    {
        const float4* x4 = (const float4*)(z_e + (size_t)n * EMB_ + ((lane >> 5) << 5));
        #pragma unroll
        for (int i = 0; i < 8; i++) {
            float4 v = x4[i];
            x[4*i] = v.x; x[4*i+1] = v.y; x[4*i+2] = v.z; x[4*i+3] = v.w;
        }
    }

    float bd = 3.0e38f;
    int   bm = 0x7FFFFFFF;
    #pragma unroll 1
    for (int c = 0; c < NCHUNK; c++) {
        if (cs3[c] >= thr) {
            // >=3 tiles of this chunk in window: exact-scan the whole chunk
            for (int tt = 0; tt < CT_PER; tt++)
                scan_tile(c * CT_PER + tt, lane, ew, wsq, x, bd, bm);
        } else {
            if (cs1[c] >= thr) scan_tile(ci1[c], lane, ew, wsq, x, bd, bm);
            if (cs2[c] >= thr) scan_tile(ci2[c], lane, ew, wsq, x, bd, bm);
        }
    }
    // wave argmin (value, lowest index on ties)
    #pragma unroll
    for (int off = 1; off < 64; off <<= 1) {
        float od = __shfl_xor(bd, off);
        int   om = __shfl_xor(bm, off);
        if (od < bd || (od == bd && om < bm)) { bd = od; bm = om; }
    }
    if (lane == 0) fidx[n] = bm;
}

// ---------------------------------------------------------------------------
// K4: gather winner rows, write out (transposed, coalesced) + z_q_flat + ind,
// reduce loss; last block writes the loss scalar.
__global__ __launch_bounds__(256) void k_finalize(
    const int* __restrict__ fidx, const float* __restrict__ ew,
    float* __restrict__ out, float* __restrict__ lacc, int* __restrict__ done)
{
    const int tid = threadIdx.x;
    const int n   = blockIdx.x * 256 + tid;
    const int idx = fidx[n];
    const int b   = n >> 10;
    const int hw  = n & 1023;

    const float4* wr = (const float4*)(ew + (size_t)idx * EMB_);
    float4* zr = (float4*)(out + ZQ_OFF + (size_t)n * EMB_);   // holds z_e
    float* outp = out + OUT_OFF + (size_t)b * (EMB_ * 1024) + hw;

    float lsum = 0.f;
    #pragma unroll
    for (int i = 0; i < 16; i++) {
        float4 w4 = wr[i];
        float4 z4 = zr[i];
        float d0 = w4.x - z4.x, d1 = w4.y - z4.y;
        float d2 = w4.z - z4.z, d3 = w4.w - z4.w;
        lsum += d0*d0 + d1*d1 + d2*d2 + d3*d3;
        zr[i] = w4;
        outp[(4*i + 0) * 1024] = w4.x;
        outp[(4*i + 1) * 1024] = w4.y;
        outp[(4*i + 2) * 1024] = w4.z;
        outp[(4*i + 3) * 1024] = w4.w;
    }
    out[IND_OFF + n] = (float)idx;

    __shared__ float red[256];
    red[tid] = lsum;
    __syncthreads();
    for (int o = 128; o > 0; o >>= 1) {
        if (tid < o) red[tid] += red[tid + o];
        __syncthreads();
    }
    if (tid == 0) {
        atomicAdd(lacc, red[0]);
        __threadfence();
        int old = atomicAdd(done, 1);
        if (old == 127) {
            float tot = atomicAdd(lacc, 0.0f);     // coherent read-back
            out[LOSS_OFF] = 12.5f * (tot / 2097152.0f);
        }
    }
}

// ---------------------------------------------------------------------------
extern "C" void kernel_launch(void* const* d_in, const int* in_sizes, int n_in,
                              void* d_out, int out_size, void* d_ws, size_t ws_size,
                              hipStream_t stream)
{
    const float* z  = (const float*)d_in[0];
    const float* pw = (const float*)d_in[1];
    const float* pb = (const float*)d_in[2];
    const float* ew = (const float*)d_in[3];
    float* out = (float*)d_out;

    char* ws = (char*)d_ws;
    float4* X4   = (float4*)(ws);                      // 5,242,880
    float4* W4   = (float4*)(ws + 5242880);            // 1,310,720
    float*  s1a  = (float*) (ws + 6553600);            // 1,048,576
    int*    i1a  = (int*)   (ws + 7602176);            // 1,048,576
    float*  s2a  = (float*) (ws + 8650752);            // 1,048,576
    int*    i2a  = (int*)   (ws + 9699328);            // 1,048,576
    float*  s3a  = (float*) (ws + 10747904);           // 1,048,576
    float*  xsq  = (float*) (ws + 11796480);           //   131,072
    float*  wsq  = (float*) (ws + 11927552);           //    32,768
    float*  wsqp = (float*) (ws + 11960320);           //       128
    int*    fidx = (int*)   (ws + 11960448);           //   131,072
    float*  lacc = (float*) (ws + 12091520);           //         4
    int*    done = (int*)   (ws + 12091524);           //         4

    float* z_e = out + ZQ_OFF;   // z_q_flat region doubles as z_e scratch

    hipLaunchKernelGGL(k_prep,    dim3(288),         dim3(256), 0, stream,
                       z, pw, pb, ew, z_e, xsq, X4, W4, wsq, wsqp, lacc, done);
    hipLaunchKernelGGL(k_pass1,   dim3(64, NCHUNK),  dim3(256), 0, stream,
                       X4, W4, s1a, i1a, s2a, i2a, s3a);
    hipLaunchKernelGGL(k_select,  dim3(8192),        dim3(256), 0, stream,
                       s1a, i1a, s2a, i2a, s3a, xsq, wsqp, wsq, ew, z_e, fidx);
    hipLaunchKernelGGL(k_finalize,dim3(128),         dim3(256), 0, stream,
                       fidx, ew, out, lacc, done);
}

// Round 5
// 218.968 us; speedup vs baseline: 1.4044x; 1.0656x over previous
//
#include <hip/hip_runtime.h>

// Problem constants
#define NPIX   32768      // B*H*W
#define NEMB_  8192
#define EMB_   64
#define CH_    128
#define NCHUNK 8          // code chunks (1024 codes = 32 tiles each)
#define CT_PER 32         // 32-code tiles per chunk
#define PXB    64         // pixels per k_selfin block
#define CAPP   2048       // LDS pair-queue capacity

// d_out layout (float elements)
#define OUT_OFF  0
#define ZQ_OFF   2097152
#define LOSS_OFF 4194304
#define IND_OFF  4194305

typedef _Float16 h8   __attribute__((ext_vector_type(8)));
typedef float    f16f __attribute__((ext_vector_type(16)));

// ---------------------------------------------------------------------------
// K1 fused: blocks [0,256): 1x1-conv projection (shuffle split-K) + xsq +
//           X-fragment pack straight from registers.
//           blocks [256,288): codebook wsq + W-fragment pack + wsqp + zero ctrs.
// X'/W' K-layout (80 slots): [0,64)=fp16(val); X slots 64,65=-0.5, W slots
// 64=wsq_hi,65=wsq_lo; rest 0.  Fragment order: F4[(t*5+s)*64 + lane],
// row m=32t+(lane&31), k=16s+8*(lane>>5)+j.
__global__ __launch_bounds__(256) void k_prep(
    const float* __restrict__ z, const float* __restrict__ pw,
    const float* __restrict__ pb, const float* __restrict__ ew,
    float* __restrict__ z_e, float* __restrict__ xsq,
    float4* __restrict__ X4, float4* __restrict__ W4,
    float* __restrict__ wsq, float* __restrict__ wsqp,
    float* __restrict__ lacc, int* __restrict__ done)
{
    const int tid = threadIdx.x;
    if (blockIdx.x >= 256) {
        // ---- codebook role ----
        const int m = (blockIdx.x - 256) * 256 + tid;
        const float4* wr = (const float4*)(ew + (size_t)m * EMB_);
        float w[EMB_];
        float s = 0.f;
        #pragma unroll
        for (int i = 0; i < 16; i++) {
            float4 v = wr[i];
            w[4*i] = v.x; w[4*i+1] = v.y; w[4*i+2] = v.z; w[4*i+3] = v.w;
            s += v.x*v.x + v.y*v.y + v.z*v.z + v.w*v.w;
        }
        wsq[m] = s;
        float sh = (float)(_Float16)s;
        float sl = s - sh;
        const int t  = m >> 5;
        const int li = m & 31;
        #pragma unroll
        for (int s5 = 0; s5 < 4; s5++) {
            #pragma unroll
            for (int h = 0; h < 2; h++) {
                h8 hh;
                #pragma unroll
                for (int j = 0; j < 8; j++) hh[j] = (_Float16)w[s5 * 16 + h * 8 + j];
                W4[(size_t)(t * 5 + s5) * 64 + h * 32 + li] = __builtin_bit_cast(float4, hh);
            }
        }
        {
            h8 hh;
            #pragma unroll
            for (int j = 0; j < 8; j++) hh[j] = (_Float16)0.f;
            hh[0] = (_Float16)sh; hh[1] = (_Float16)sl;
            W4[(size_t)(t * 5 + 4) * 64 + 0 * 32 + li] = __builtin_bit_cast(float4, hh);
            #pragma unroll
            for (int j = 0; j < 8; j++) hh[j] = (_Float16)0.f;
            W4[(size_t)(t * 5 + 4) * 64 + 1 * 32 + li] = __builtin_bit_cast(float4, hh);
        }
        __shared__ float red[256];
        red[tid] = s;
        __syncthreads();
        for (int o = 128; o > 0; o >>= 1) {
            if (tid < o) red[tid] = fmaxf(red[tid], red[tid + o]);
            __syncthreads();
        }
        if (tid == 0) wsqp[blockIdx.x - 256] = red[0];
        if (blockIdx.x == 256 && tid == 0) { *lacc = 0.f; *done = 0; }
        return;
    }
    // ---- projection role: wave = 32 pixels x split-K-2 (lane>>5 = K-half) ----
    __shared__ __align__(16) float wT[CH_ * EMB_];   // [c][e] 32KB, broadcast reads
    for (int i = tid; i < CH_ * EMB_; i += 256) {
        int c = i >> 6, e = i & 63;
        wT[i] = pw[e * CH_ + c];
    }
    __syncthreads();

    const int lane = tid & 63;
    const int wv   = tid >> 6;
    const int half = lane >> 5;
    const int n    = blockIdx.x * 128 + wv * 32 + (lane & 31);
    const int b    = n >> 10;
    const int hw   = n & 1023;
    const float* zp = z + (size_t)b * (CH_ * 1024) + (size_t)(half * 64) * 1024 + hw;

    float acc[EMB_];
    #pragma unroll
    for (int i = 0; i < EMB_; i++) acc[i] = 0.f;
    for (int c = 0; c < 64; c++) {
        float zv = zp[(size_t)c * 1024];
        const float4* w4 = (const float4*)(wT + (half * 64 + c) * EMB_);
        #pragma unroll
        for (int i = 0; i < 16; i++) {
            float4 v = w4[i];
            acc[4*i]   = fmaf(zv, v.x, acc[4*i]);
            acc[4*i+1] = fmaf(zv, v.y, acc[4*i+1]);
            acc[4*i+2] = fmaf(zv, v.z, acc[4*i+2]);
            acc[4*i+3] = fmaf(zv, v.w, acc[4*i+3]);
        }
    }
    // combine the two K-halves in-register
    #pragma unroll
    for (int e = 0; e < EMB_; e++) acc[e] += __shfl_xor(acc[e], 32);

    if (half == 0) {
        const float4* bb = (const float4*)pb;
        float4* zo = (float4*)(z_e + (size_t)n * EMB_);
        float s = 0.f;
        #pragma unroll
        for (int i = 0; i < 16; i++) {
            float4 bv = bb[i];
            acc[4*i]   += bv.x; acc[4*i+1] += bv.y;
            acc[4*i+2] += bv.z; acc[4*i+3] += bv.w;
            zo[i] = make_float4(acc[4*i], acc[4*i+1], acc[4*i+2], acc[4*i+3]);
            s += acc[4*i]*acc[4*i] + acc[4*i+1]*acc[4*i+1]
               + acc[4*i+2]*acc[4*i+2] + acc[4*i+3]*acc[4*i+3];
        }
        xsq[n] = s;
        // pack X4 from registers (t uniform per wave, li = lane&31)
        const int t  = n >> 5;
        const int li = n & 31;
        #pragma unroll
        for (int s5 = 0; s5 < 4; s5++) {
            #pragma unroll
            for (int h = 0; h < 2; h++) {
                h8 hh;
                #pragma unroll
                for (int j = 0; j < 8; j++)
                    hh[j] = (_Float16)acc[s5 * 16 + h * 8 + j];
                X4[(size_t)(t * 5 + s5) * 64 + h * 32 + li] = __builtin_bit_cast(float4, hh);
            }
        }
        {
            h8 hh;
            #pragma unroll
            for (int j = 0; j < 8; j++) hh[j] = (_Float16)0.f;
            hh[0] = (_Float16)-0.5f; hh[1] = (_Float16)-0.5f;
            X4[(size_t)(t * 5 + 4) * 64 + 0 * 32 + li] = __builtin_bit_cast(float4, hh);
            #pragma unroll
            for (int j = 0; j < 8; j++) hh[j] = (_Float16)0.f;
            X4[(size_t)(t * 5 + 4) * 64 + 1 * 32 + li] = __builtin_bit_cast(float4, hh);
        }
    }
}

// ---------------------------------------------------------------------------
// K2: coarse MFMA pass, max-only epilogue -> per-chunk top-3 TILE maxima
// (+ tile indices for top-2) per pixel.  grid (64, NCHUNK), block 256.
__global__ __launch_bounds__(256, 2) void k_pass1(
    const float4* __restrict__ X4, const float4* __restrict__ W4,
    float* __restrict__ s1a, int* __restrict__ i1a,
    float* __restrict__ s2a, int* __restrict__ i2a,
    float* __restrict__ s3a)
{
    const int lane  = threadIdx.x & 63;
    const int wv    = threadIdx.x >> 6;
    const int chunk = blockIdx.y;
    const int pt0   = blockIdx.x * 16 + wv * 4;

    h8 bfr[4][5];
    #pragma unroll
    for (int j = 0; j < 4; j++)
        #pragma unroll
        for (int s = 0; s < 5; s++)
            bfr[j][s] = __builtin_bit_cast(h8, X4[(size_t)((pt0 + j) * 5 + s) * 64 + lane]);

    float s1[4], s2[4], s3[4];
    int   i1[4], i2[4];
    #pragma unroll
    for (int j = 0; j < 4; j++) {
        s1[j] = -3.0e38f; s2[j] = -3.0e38f; s3[j] = -3.0e38f;
        i1[j] = 0; i2[j] = 0;
    }

    const f16f zero16 = {0,0,0,0,0,0,0,0,0,0,0,0,0,0,0,0};

    for (int tt = 0; tt < CT_PER; tt++) {
        const int gt = chunk * CT_PER + tt;          // global tile id
        const float4* wp = W4 + (size_t)gt * 320 + lane;
        float4 a4[5];
        #pragma unroll
        for (int s = 0; s < 5; s++) a4[s] = wp[s * 64];

        f16f acc[4];
        #pragma unroll
        for (int j = 0; j < 4; j++) acc[j] = zero16;
        #pragma unroll
        for (int s = 0; s < 5; s++) {
            h8 a = __builtin_bit_cast(h8, a4[s]);
            #pragma unroll
            for (int j = 0; j < 4; j++)
                acc[j] = __builtin_amdgcn_mfma_f32_32x32x16_f16(a, bfr[j][s], acc[j], 0, 0, 0);
        }
        #pragma unroll
        for (int j = 0; j < 4; j++) {
            // max tree over 16 regs (max3-friendly shapes)
            float t0 = fmaxf(fmaxf(acc[j][0],  acc[j][1]),  acc[j][2]);
            float t1 = fmaxf(fmaxf(acc[j][3],  acc[j][4]),  acc[j][5]);
            float t2 = fmaxf(fmaxf(acc[j][6],  acc[j][7]),  acc[j][8]);
            float t3 = fmaxf(fmaxf(acc[j][9],  acc[j][10]), acc[j][11]);
            float t4 = fmaxf(fmaxf(acc[j][12], acc[j][13]), acc[j][14]);
            float v  = fmaxf(fmaxf(fmaxf(t0, t1), fmaxf(t2, t3)),
                             fmaxf(t4, acc[j][15]));
            v = fmaxf(v, __shfl_xor(v, 32));         // full 32-row tile max
            // top-3 tile update (identical in both lane halves)
            bool c1 = v > s1[j];
            bool c2 = v > s2[j];
            int  cand = c1 ? i1[j] : gt;
            i2[j] = c2 ? cand : i2[j];
            s3[j] = fmaxf(fminf(s2[j], v), s3[j]);
            s3[j] = fminf(s3[j], fmaxf(s2[j], v));
            s2[j] = fmaxf(fminf(s1[j], v), fminf(s2[j], fmaxf(s1[j], v)));
            i1[j] = c1 ? gt : i1[j];
            s1[j] = fmaxf(s1[j], v);
        }
    }

    if (lane < 32) {
        #pragma unroll
        for (int j = 0; j < 4; j++) {
            const int p = (pt0 + j) * 32 + lane;
            const size_t o = (size_t)chunk * NPIX + p;
            s1a[o] = s1[j]; i1a[o] = i1[j];
            s2a[o] = s2[j]; i2a[o] = i2[j];
            s3a[o] = s3[j];
        }
    }
}

// ---------------------------------------------------------------------------
// ordered-float key: lexicographic (dist, index) min == np argmin semantics
__device__ __forceinline__ unsigned long long pack_key(float d, int m)
{
    unsigned fb = __float_as_uint(d);
    fb ^= ((int)fb < 0) ? 0xFFFFFFFFu : 0x80000000u;
    return ((unsigned long long)fb << 32) | (unsigned)m;
}

// per-lane distance for code (t*32 + lane&31), half-dims (lane>>5)
__device__ __forceinline__ unsigned long long lane_key(
    int t, int lane, const float* __restrict__ ew, const float* __restrict__ wsq,
    const float4* __restrict__ x4)
{
    const int m = t * 32 + (lane & 31);
    const float4* w4 = (const float4*)(ew + (size_t)m * EMB_ + ((lane >> 5) << 5));
    float dp = 0.f;
    #pragma unroll
    for (int i = 0; i < 8; i++) {
        float4 wv = w4[i];
        float4 xv = x4[i];
        dp = fmaf(wv.x, xv.x, dp); dp = fmaf(wv.y, xv.y, dp);
        dp = fmaf(wv.z, xv.z, dp); dp = fmaf(wv.w, xv.w, dp);
    }
    dp += __shfl_xor(dp, 32);
    float d = fmaf(-2.f, dp, wsq[m]);
    return pack_key(d, m);
}

// ---------------------------------------------------------------------------
// K3 fused select+finalize: block = 64 pixels.  Lane-parallel stats ->
// LDS pair queue -> wave-drained exact scans -> in-kernel finalize + loss.
__global__ __launch_bounds__(256) void k_selfin(
    const float* __restrict__ s1a, const int* __restrict__ i1a,
    const float* __restrict__ s2a, const int* __restrict__ i2a,
    const float* __restrict__ s3a, const float* __restrict__ xsq,
    const float* __restrict__ wsqp, const float* __restrict__ wsq,
    const float* __restrict__ ew, const float* __restrict__ z_e,
    float* __restrict__ out, float* __restrict__ lacc, int* __restrict__ done)
{
    __shared__ __align__(16) float xs[PXB][68];      // z_e, later winner rows
    __shared__ float tmp1[512];
    __shared__ float thr_s[PXB];
    __shared__ int   pairs[CAPP];
    __shared__ unsigned long long wbest[4][PXB];
    __shared__ int   winner_s[PXB];
    __shared__ int   smask[PXB];
    __shared__ int   npair_s;
    __shared__ float wm_s;
    __shared__ float lred[256];

    const int tid  = threadIdx.x;
    const int wv   = tid >> 6;
    const int lane = tid & 63;
    const int n0   = blockIdx.x * PXB;

    if (tid == 0) npair_s = 0;
    if (tid < PXB) smask[tid] = 0;
    wbest[wv][lane] = ~0ULL;
    if (tid < 32) {
        float w = wsqp[tid];
        #pragma unroll
        for (int o = 16; o > 0; o >>= 1) w = fmaxf(w, __shfl_xor(w, o));
        if (tid == 0) wm_s = w;
    }
    // stage x (64 px * 64 floats)
    #pragma unroll
    for (int k = 0; k < 4; k++) {
        int idx = k * 256 + tid;
        int px = idx >> 4, i = idx & 15;
        float4 v = *(const float4*)(z_e + (size_t)(n0 + px) * EMB_ + i * 4);
        ((float4*)&xs[px][0])[i] = v;
    }
    // stats cells: 512 cells over 256 threads
    float cs1[2], cs2[2], cs3[2];
    int   ci1[2], ci2[2];
    #pragma unroll
    for (int k = 0; k < 2; k++) {
        int cell = tid + k * 256;
        int c = cell & 7, p = cell >> 3;
        size_t o = (size_t)c * NPIX + n0 + p;
        cs1[k] = s1a[o]; ci1[k] = i1a[o];
        cs2[k] = s2a[o]; ci2[k] = i2a[o];
        cs3[k] = s3a[o];
        tmp1[cell] = cs1[k];
    }
    __syncthreads();
    if (tid < PXB) {
        float s1g = tmp1[tid * 8];
        #pragma unroll
        for (int c = 1; c < 8; c++) s1g = fmaxf(s1g, tmp1[tid * 8 + c]);
        float E = 0.00125f * sqrtf(xsq[n0 + tid] * wm_s) + 1e-5f * wm_s + 3e-4f;
        thr_s[tid] = s1g - 2.0f * E;
    }
    __syncthreads();
    // push candidate (pixel,tile) pairs
    #pragma unroll
    for (int k = 0; k < 2; k++) {
        int cell = tid + k * 256;
        int c = cell & 7, p = cell >> 3;
        float th = thr_s[p];
        if (cs3[k] >= th) {
            int pos = atomicAdd(&npair_s, 32);
            if (pos + 32 <= CAPP) {
                for (int t = 0; t < 32; t++) pairs[pos + t] = (p << 8) | (c * 32 + t);
            } else {
                for (int t = 0; t < 32; t++)
                    if (pos + t < CAPP) pairs[pos + t] = -1;   // no holes
                smask[p] = 1;
            }
        } else {
            if (cs1[k] >= th) {
                int pos = atomicAdd(&npair_s, 1);
                if (pos < CAPP) pairs[pos] = (p << 8) | ci1[k]; else smask[p] = 1;
            }
            if (cs2[k] >= th) {
                int pos = atomicAdd(&npair_s, 1);
                if (pos < CAPP) pairs[pos] = (p << 8) | ci2[k]; else smask[p] = 1;
            }
        }
    }
    __syncthreads();
    const int np = min(npair_s, CAPP);

    // drain pair queue (wave-level round-robin)
    for (int i = wv; i < np; i += 4) {
        int pr = pairs[i];
        if (pr < 0) continue;
        int p = pr >> 8, t = pr & 255;
        if (smask[p]) continue;
        const float4* x4 = (const float4*)&xs[p][(lane >> 5) << 5];
        unsigned long long key = lane_key(t, lane, ew, wsq, x4);
        #pragma unroll
        for (int o = 1; o < 32; o <<= 1) {
            unsigned long long ok = __shfl_xor(key, o);
            key = ok < key ? ok : key;
        }
        if (lane == 0) {
            unsigned long long cur = wbest[wv][p];
            wbest[wv][p] = key < cur ? key : cur;
        }
    }
    // overflow fallback: full 256-tile rescan (statistically never)
    for (int p = wv; p < PXB; p += 4) {
        if (!smask[p]) continue;
        const float4* x4 = (const float4*)&xs[p][(lane >> 5) << 5];
        unsigned long long bk = ~0ULL;
        for (int t = 0; t < 256; t++) {
            unsigned long long k2 = lane_key(t, lane, ew, wsq, x4);
            bk = k2 < bk ? k2 : bk;   // note lane_key includes the dp exchange only
        }
        #pragma unroll
        for (int o = 1; o < 32; o <<= 1) {
            unsigned long long ok = __shfl_xor(bk, o);
            bk = ok < bk ? ok : bk;
        }
        if (lane == 0) {
            unsigned long long cur = wbest[wv][p];
            wbest[wv][p] = bk < cur ? bk : cur;
        }
    }
    __syncthreads();
    if (tid < PXB) {
        unsigned long long k0 = wbest[0][tid];
        unsigned long long k1 = wbest[1][tid];
        unsigned long long k2 = wbest[2][tid];
        unsigned long long k3 = wbest[3][tid];
        k0 = k1 < k0 ? k1 : k0;
        k2 = k3 < k2 ? k3 : k2;
        k0 = k2 < k0 ? k2 : k0;
        int win = (int)(unsigned)(k0 & 0xFFFFFFFFULL);
        winner_s[tid] = win;
        out[IND_OFF + n0 + tid] = (float)win;
    }
    __syncthreads();
    // gather winner rows, z_q writes, loss partial; overwrite xs with w rows
    float lsum = 0.f;
    {
        const int px = tid >> 2, q = tid & 3;
        const int win = winner_s[px];
        const float4* wr = (const float4*)(ew + (size_t)win * EMB_ + q * 16);
        float4* zq4 = (float4*)(out + ZQ_OFF + (size_t)(n0 + px) * EMB_ + q * 16);
        float4* xr  = (float4*)&xs[px][q * 16];
        #pragma unroll
        for (int i = 0; i < 4; i++) {
            float4 w4 = wr[i];
            float4 z4 = xr[i];
            float d0 = w4.x - z4.x, d1 = w4.y - z4.y;
            float d2 = w4.z - z4.z, d3 = w4.w - z4.w;
            lsum += d0*d0 + d1*d1 + d2*d2 + d3*d3;
            xr[i] = w4;
            zq4[i] = w4;
        }
    }
    __syncthreads();
    // transposed out writes: wave wv handles e in [wv*16, wv*16+16), lane = px
    {
        const int b   = n0 >> 10;
        const int hw0 = n0 & 1023;
        float* ob = out + OUT_OFF + (size_t)b * (EMB_ * 1024) + hw0 + lane;
        #pragma unroll
        for (int e = wv * 16; e < wv * 16 + 16; e++)
            ob[(size_t)e * 1024] = xs[lane][e];
    }
    // loss reduction
    lred[tid] = lsum;
    __syncthreads();
    for (int o = 128; o > 0; o >>= 1) {
        if (tid < o) lred[tid] += lred[tid + o];
        __syncthreads();
    }
    if (tid == 0) {
        atomicAdd(lacc, lred[0]);
        __threadfence();
        int old = atomicAdd(done, 1);
        if (old == (int)gridDim.x - 1) {
            float tot = atomicAdd(lacc, 0.0f);
            out[LOSS_OFF] = 12.5f * (tot / 2097152.0f);
        }
    }
}

// ---------------------------------------------------------------------------
extern "C" void kernel_launch(void* const* d_in, const int* in_sizes, int n_in,
                              void* d_out, int out_size, void* d_ws, size_t ws_size,
                              hipStream_t stream)
{
    const float* z  = (const float*)d_in[0];
    const float* pw = (const float*)d_in[1];
    const float* pb = (const float*)d_in[2];
    const float* ew = (const float*)d_in[3];
    float* out = (float*)d_out;

    char* ws = (char*)d_ws;
    float4* X4   = (float4*)(ws);                      // 5,242,880
    float4* W4   = (float4*)(ws + 5242880);            // 1,310,720
    float*  s1a  = (float*) (ws + 6553600);            // 1,048,576
    int*    i1a  = (int*)   (ws + 7602176);            // 1,048,576
    float*  s2a  = (float*) (ws + 8650752);            // 1,048,576
    int*    i2a  = (int*)   (ws + 9699328);            // 1,048,576
    float*  s3a  = (float*) (ws + 10747904);           // 1,048,576
    float*  xsq  = (float*) (ws + 11796480);           //   131,072
    float*  wsq  = (float*) (ws + 11927552);           //    32,768
    float*  wsqp = (float*) (ws + 11960320);           //       128
    float*  lacc = (float*) (ws + 11960448);           //         4
    int*    done = (int*)   (ws + 11960452);           //         4

    float* z_e = out + ZQ_OFF;   // z_q_flat region doubles as z_e scratch

    hipLaunchKernelGGL(k_prep,   dim3(288),        dim3(256), 0, stream,
                       z, pw, pb, ew, z_e, xsq, X4, W4, wsq, wsqp, lacc, done);
    hipLaunchKernelGGL(k_pass1,  dim3(64, NCHUNK), dim3(256), 0, stream,
                       X4, W4, s1a, i1a, s2a, i2a, s3a);
    hipLaunchKernelGGL(k_selfin, dim3(NPIX / PXB), dim3(256), 0, stream,
                       s1a, i1a, s2a, i2a, s3a, xsq, wsqp, wsq, ew, z_e,
                       out, lacc, done);
}

// Round 6
// 208.691 us; speedup vs baseline: 1.4735x; 1.0492x over previous
//
#include <hip/hip_runtime.h>

// Problem constants
#define NPIX   32768      // B*H*W
#define NEMB_  8192
#define EMB_   64
#define CH_    128
#define NCHUNK 8          // 8 chunks x 32 tiles x 32 codes
#define CAPP   1024       // LDS pair-queue capacity

// d_out layout (float elements)
#define OUT_OFF  0
#define ZQ_OFF   2097152
#define LOSS_OFF 4194304
#define IND_OFF  4194305

typedef _Float16 h8   __attribute__((ext_vector_type(8)));
typedef float    f16f __attribute__((ext_vector_type(16)));

// ---------------------------------------------------------------------------
// K1: blocks [0,256): tiled-GEMM projection (128 px/block) -> z_e, xsq.
//     blocks [256,288): codebook wsq + W-fragment pack + wsqp + zero ctrs.
// W' K-layout (80 slots): [0,64)=fp16(w); 64=wsq_hi, 65=wsq_lo; rest 0.
// Fragment order: W4[(t*5+s)*64 + lane]: code m=32t+(lane&31), k=16s+8(lane>>5)+j
__global__ __launch_bounds__(256) void k_prep(
    const float* __restrict__ z, const float* __restrict__ pw,
    const float* __restrict__ pb, const float* __restrict__ ew,
    float* __restrict__ z_e, float* __restrict__ xsq,
    float4* __restrict__ W4, float* __restrict__ wsq,
    float* __restrict__ wsqp, float* __restrict__ lacc, int* __restrict__ done)
{
    const int tid = threadIdx.x;
    if (blockIdx.x >= 256) {
        // ---- codebook role (r5-validated) ----
        const int m = (blockIdx.x - 256) * 256 + tid;
        const float4* wr = (const float4*)(ew + (size_t)m * EMB_);
        float w[EMB_];
        float s = 0.f;
        #pragma unroll
        for (int i = 0; i < 16; i++) {
            float4 v = wr[i];
            w[4*i] = v.x; w[4*i+1] = v.y; w[4*i+2] = v.z; w[4*i+3] = v.w;
            s += v.x*v.x + v.y*v.y + v.z*v.z + v.w*v.w;
        }
        wsq[m] = s;
        float sh = (float)(_Float16)s;
        float sl = s - sh;
        const int t  = m >> 5;
        const int li = m & 31;
        #pragma unroll
        for (int s5 = 0; s5 < 4; s5++) {
            #pragma unroll
            for (int h = 0; h < 2; h++) {
                h8 hh;
                #pragma unroll
                for (int j = 0; j < 8; j++) hh[j] = (_Float16)w[s5 * 16 + h * 8 + j];
                W4[(size_t)(t * 5 + s5) * 64 + h * 32 + li] = __builtin_bit_cast(float4, hh);
            }
        }
        {
            h8 hh;
            #pragma unroll
            for (int j = 0; j < 8; j++) hh[j] = (_Float16)0.f;
            hh[0] = (_Float16)sh; hh[1] = (_Float16)sl;
            W4[(size_t)(t * 5 + 4) * 64 + 0 * 32 + li] = __builtin_bit_cast(float4, hh);
            #pragma unroll
            for (int j = 0; j < 8; j++) hh[j] = (_Float16)0.f;
            W4[(size_t)(t * 5 + 4) * 64 + 1 * 32 + li] = __builtin_bit_cast(float4, hh);
        }
        __shared__ float red[256];
        red[tid] = s;
        __syncthreads();
        for (int o = 128; o > 0; o >>= 1) {
            if (tid < o) red[tid] = fmaxf(red[tid], red[tid + o]);
            __syncthreads();
        }
        if (tid == 0) wsqp[blockIdx.x - 256] = red[0];
        if (blockIdx.x == 256 && tid == 0) { *lacc = 0.f; *done = 0; }
        return;
    }
    // ---- projection role: 128px x 64e tile, thread = 4px x 8e ----
    __shared__ __align__(16) float zs[32 * 128];   // [c][px] 16 KB
    __shared__ __align__(16) float ws[32 * 64];    // [c][e]   8 KB
    __shared__ float xp[8 * 128];                  // [eg][px] 4 KB
    const int eg  = tid >> 5;     // 0..7
    const int pxg = tid & 31;     // 0..31
    const int n0  = blockIdx.x * 128;
    const int b   = n0 >> 10;
    const int hw0 = n0 & 1023;
    const float* zb = z + (size_t)b * (CH_ * 1024) + hw0;

    float acc[4][8];
    #pragma unroll
    for (int i = 0; i < 4; i++)
        #pragma unroll
        for (int j = 0; j < 8; j++) acc[i][j] = 0.f;

    for (int c0 = 0; c0 < CH_; c0 += 32) {
        __syncthreads();
        #pragma unroll
        for (int l = 0; l < 16; l++) {
            int idx = l * 256 + tid;
            int c = idx >> 7, px = idx & 127;
            zs[c * 128 + px] = zb[(size_t)(c0 + c) * 1024 + px];
        }
        #pragma unroll
        for (int l = 0; l < 8; l++) {
            int idx = l * 256 + tid;
            int c = idx >> 6, e = idx & 63;
            ws[c * 64 + e] = pw[e * CH_ + c0 + c];
        }
        __syncthreads();
        for (int c = 0; c < 32; c++) {
            float4 zv = *(const float4*)(zs + c * 128 + pxg * 4);
            float4 w0 = *(const float4*)(ws + c * 64 + eg * 8);
            float4 w1 = *(const float4*)(ws + c * 64 + eg * 8 + 4);
            float zz[4] = {zv.x, zv.y, zv.z, zv.w};
            float wwv[8] = {w0.x, w0.y, w0.z, w0.w, w1.x, w1.y, w1.z, w1.w};
            #pragma unroll
            for (int i = 0; i < 4; i++)
                #pragma unroll
                for (int j = 0; j < 8; j++)
                    acc[i][j] = fmaf(zz[i], wwv[j], acc[i][j]);
        }
    }
    // bias + stores + xsq partials
    float4 b0 = ((const float4*)pb)[eg * 2];
    float4 b1 = ((const float4*)pb)[eg * 2 + 1];
    float bs[8] = {b0.x, b0.y, b0.z, b0.w, b1.x, b1.y, b1.z, b1.w};
    #pragma unroll
    for (int i = 0; i < 4; i++) {
        const int px = pxg * 4 + i;
        float v[8];
        float sq = 0.f;
        #pragma unroll
        for (int j = 0; j < 8; j++) { v[j] = acc[i][j] + bs[j]; sq += v[j] * v[j]; }
        float4* zo = (float4*)(z_e + (size_t)(n0 + px) * EMB_ + eg * 8);
        zo[0] = make_float4(v[0], v[1], v[2], v[3]);
        zo[1] = make_float4(v[4], v[5], v[6], v[7]);
        xp[eg * 128 + px] = sq;
    }
    __syncthreads();
    if (tid < 128) {
        float s = 0.f;
        #pragma unroll
        for (int e = 0; e < 8; e++) s += xp[e * 128 + tid];
        xsq[n0 + tid] = s;
    }
}

// ---------------------------------------------------------------------------
// ordered-float key: lexicographic (dist, index) min == np argmin semantics
__device__ __forceinline__ unsigned long long pack_key(float d, int m)
{
    unsigned fb = __float_as_uint(d);
    fb ^= ((int)fb < 0) ? 0xFFFFFFFFu : 0x80000000u;
    return ((unsigned long long)fb << 32) | (unsigned)m;
}

// exact per-lane distance key for code m against xs row xr (broadcast reads)
__device__ __forceinline__ unsigned long long lane_key2(
    int m, const float* __restrict__ xr,
    const float* __restrict__ ew, const float* __restrict__ wsq)
{
    const float4* w4 = (const float4*)(ew + (size_t)m * EMB_);
    const float4* x4 = (const float4*)xr;
    float a0 = 0.f, a1 = 0.f;
    #pragma unroll
    for (int i = 0; i < 8; i++) {
        float4 wv = w4[2*i], xv = x4[2*i];
        float4 wu = w4[2*i+1], xu = x4[2*i+1];
        a0 = fmaf(wv.x, xv.x, a0); a0 = fmaf(wv.y, xv.y, a0);
        a0 = fmaf(wv.z, xv.z, a0); a0 = fmaf(wv.w, xv.w, a0);
        a1 = fmaf(wu.x, xu.x, a1); a1 = fmaf(wu.y, xu.y, a1);
        a1 = fmaf(wu.z, xu.z, a1); a1 = fmaf(wu.w, xu.w, a1);
    }
    float d = fmaf(-2.f, a0 + a1, wsq[m]);
    return pack_key(d, m);
}

// ---------------------------------------------------------------------------
// K2 fused: coarse MFMA scan (wave = 2 chunks x 4 px-tiles) -> LDS stats ->
// certify -> data-parallel exact drain -> finalize + loss.  grid 256 x 256.
__global__ __launch_bounds__(256, 1) void k_fused(
    const float4* __restrict__ W4, const float* __restrict__ z_e,
    const float* __restrict__ xsq, const float* __restrict__ wsqp,
    const float* __restrict__ wsq, const float* __restrict__ ew,
    float* __restrict__ out, float* __restrict__ lacc, int* __restrict__ done)
{
    __shared__ __align__(16) float xs[128 * 68];     // z_e rows, later winners
    __shared__ float s1s[1024], s2s[1024], s3s[1024];
    __shared__ short i1s[1024], i2s[1024];
    __shared__ unsigned long long wbest[512];        // [wave][px]
    __shared__ int   pairs[CAPP];
    __shared__ int   winner_s[128];
    __shared__ int   smask[128];
    __shared__ float thr_s[128];
    __shared__ float lred[256];
    __shared__ int   npair_s;
    __shared__ float wm_s;

    const int tid  = threadIdx.x;
    const int wv   = tid >> 6;
    const int lane = tid & 63;
    const int n0   = blockIdx.x * 128;
    const int hlf  = lane >> 5;

    // ---- B-fragments from z_e (+ stage xs via wave 0) ----
    h8 bfr[4][5];
    #pragma unroll
    for (int j = 0; j < 4; j++) {
        const int px = j * 32 + (lane & 31);
        const float* zr = z_e + (size_t)(n0 + px) * EMB_ + (hlf << 3);
        #pragma unroll
        for (int s5 = 0; s5 < 4; s5++) {
            float4 u0 = *(const float4*)(zr + s5 * 16);
            float4 u1 = *(const float4*)(zr + s5 * 16 + 4);
            h8 hh;
            hh[0]=(_Float16)u0.x; hh[1]=(_Float16)u0.y; hh[2]=(_Float16)u0.z; hh[3]=(_Float16)u0.w;
            hh[4]=(_Float16)u1.x; hh[5]=(_Float16)u1.y; hh[6]=(_Float16)u1.z; hh[7]=(_Float16)u1.w;
            bfr[j][s5] = hh;
            if (wv == 0) {
                float* xd = xs + px * 68 + s5 * 16 + (hlf << 3);
                *(float4*)xd = u0;
                *(float4*)(xd + 4) = u1;
            }
        }
        h8 hh;
        #pragma unroll
        for (int q = 0; q < 8; q++) hh[q] = (_Float16)0.f;
        if (hlf == 0) { hh[0] = (_Float16)-0.5f; hh[1] = (_Float16)-0.5f; }
        bfr[j][4] = hh;
    }

    // ---- coarse scan: chunks 2wv, 2wv+1 (tiles wv*64 .. +63) ----
    const int tb = wv * 64;
    const f16f kzero = {0,0,0,0,0,0,0,0,0,0,0,0,0,0,0,0};
    float s1[4], s2[4], s3[4];
    int   i1[4], i2[4];
    #pragma unroll
    for (int j = 0; j < 4; j++) { s1[j]=s2[j]=s3[j]=-3.0e38f; i1[j]=i2[j]=0; }

    float4 a4[5];
    {
        const float4* wp = W4 + (size_t)tb * 320 + lane;
        #pragma unroll
        for (int s = 0; s < 5; s++) a4[s] = wp[s * 64];
    }
    for (int tt = 0; tt < 64; tt++) {
        const int gt = tb + tt;
        const int tn = tb + (tt < 63 ? tt + 1 : tt);
        const float4* wn = W4 + (size_t)tn * 320 + lane;
        float4 nx[5];
        #pragma unroll
        for (int s = 0; s < 5; s++) nx[s] = wn[s * 64];

        f16f acc[4];
        #pragma unroll
        for (int j = 0; j < 4; j++)
            acc[j] = __builtin_amdgcn_mfma_f32_32x32x16_f16(
                __builtin_bit_cast(h8, a4[0]), bfr[j][0], kzero, 0, 0, 0);
        #pragma unroll
        for (int s = 1; s < 5; s++) {
            h8 a = __builtin_bit_cast(h8, a4[s]);
            #pragma unroll
            for (int j = 0; j < 4; j++)
                acc[j] = __builtin_amdgcn_mfma_f32_32x32x16_f16(a, bfr[j][s], acc[j], 0, 0, 0);
        }
        #pragma unroll
        for (int j = 0; j < 4; j++) {
            float t0 = fmaxf(fmaxf(acc[j][0],  acc[j][1]),  acc[j][2]);
            float t1 = fmaxf(fmaxf(acc[j][3],  acc[j][4]),  acc[j][5]);
            float t2 = fmaxf(fmaxf(acc[j][6],  acc[j][7]),  acc[j][8]);
            float t3 = fmaxf(fmaxf(acc[j][9],  acc[j][10]), acc[j][11]);
            float t4 = fmaxf(fmaxf(acc[j][12], acc[j][13]), acc[j][14]);
            float v  = fmaxf(fmaxf(fmaxf(t0, t1), fmaxf(t2, t3)),
                             fmaxf(t4, acc[j][15]));
            v = fmaxf(v, __shfl_xor(v, 32));
            bool c1 = v > s1[j];
            bool c2 = v > s2[j];
            int  cand = c1 ? i1[j] : gt;
            i2[j] = c2 ? cand : i2[j];
            s3[j] = fmaxf(fminf(s2[j], v), s3[j]);
            s3[j] = fminf(s3[j], fmaxf(s2[j], v));
            s2[j] = fmaxf(fminf(s1[j], v), fminf(s2[j], fmaxf(s1[j], v)));
            i1[j] = c1 ? gt : i1[j];
            s1[j] = fmaxf(s1[j], v);
        }
        if (tt == 31 || tt == 63) {
            const int ch = 2 * wv + (tt >> 5);
            if (lane < 32) {
                #pragma unroll
                for (int j = 0; j < 4; j++) {
                    const int cell = (j * 32 + lane) * 8 + ch;
                    s1s[cell] = s1[j]; s2s[cell] = s2[j]; s3s[cell] = s3[j];
                    i1s[cell] = (short)i1[j]; i2s[cell] = (short)i2[j];
                }
            }
            #pragma unroll
            for (int j = 0; j < 4; j++) { s1[j]=s2[j]=s3[j]=-3.0e38f; i1[j]=i2[j]=0; }
        }
        #pragma unroll
        for (int s = 0; s < 5; s++) a4[s] = nx[s];
    }
    __syncthreads();

    // ---- certify setup ----
    if (tid < 32) {
        float w = wsqp[tid];
        #pragma unroll
        for (int o = 16; o > 0; o >>= 1) w = fmaxf(w, __shfl_xor(w, o));
        if (tid == 0) wm_s = w;
    }
    if (tid == 0) npair_s = 0;
    for (int i = tid; i < 512; i += 256) wbest[i] = ~0ULL;
    if (tid < 128) smask[tid] = 0;
    __syncthreads();
    if (tid < 128) {
        float s1g = s1s[tid * 8];
        #pragma unroll
        for (int c = 1; c < 8; c++) s1g = fmaxf(s1g, s1s[tid * 8 + c]);
        float E = 0.00125f * sqrtf(xsq[n0 + tid] * wm_s) + 1e-5f * wm_s + 3e-4f;
        thr_s[tid] = s1g - 2.0f * E;
    }
    __syncthreads();
    // ---- push candidate (px,tile) pairs ----
    {
        const int base = tid * 4;
        const int p    = base >> 3;
        const float th = thr_s[p];
        #pragma unroll
        for (int k = 0; k < 4; k++) {
            const int cell = base + k;
            if (s3s[cell] >= th) {
                const int c = cell & 7;
                int pos = atomicAdd(&npair_s, 32);
                if (pos + 32 <= CAPP) {
                    for (int t = 0; t < 32; t++) pairs[pos + t] = (p << 8) | (c * 32 + t);
                } else {
                    for (int t = 0; t < 32; t++)
                        if (pos + t < CAPP) pairs[pos + t] = -1;
                    smask[p] = 1;
                }
            } else {
                if (s1s[cell] >= th) {
                    int pos = atomicAdd(&npair_s, 1);
                    if (pos < CAPP) pairs[pos] = (p << 8) | (int)i1s[cell]; else smask[p] = 1;
                }
                if (s2s[cell] >= th) {
                    int pos = atomicAdd(&npair_s, 1);
                    if (pos < CAPP) pairs[pos] = (p << 8) | (int)i2s[cell]; else smask[p] = 1;
                }
            }
        }
    }
    __syncthreads();
    const int np = min(npair_s, CAPP);

    // ---- drain: 2 pairs per wave-batch, lane = code ----
    for (int i = wv * 2; i < np; i += 8) {
        const int pr = (lane < 32) ? pairs[i] : ((i + 1 < np) ? pairs[i + 1] : -1);
        const int p  = (pr >= 0) ? (pr >> 8) : 0;
        const bool ok = (pr >= 0) && !smask[p];
        unsigned long long key = ~0ULL;
        if (ok) {
            const int m = (pr & 255) * 32 + (lane & 31);
            key = lane_key2(m, xs + p * 68, ew, wsq);
        }
        #pragma unroll
        for (int o = 1; o < 32; o <<= 1) {
            unsigned long long ok2 = __shfl_xor(key, o);
            key = ok2 < key ? ok2 : key;
        }
        if ((lane & 31) == 0 && ok)
            atomicMin(&wbest[wv * 128 + p], key);
    }
    // overflow fallback: full codebook rescan (statistically never)
    for (int p = wv; p < 128; p += 4) {
        if (!smask[p]) continue;
        const float* xr = xs + p * 68;
        unsigned long long bk = ~0ULL;
        for (int it = 0; it < 128; it++) {
            const int m = (2 * it + hlf) * 32 + (lane & 31);
            unsigned long long k2 = lane_key2(m, xr, ew, wsq);
            bk = k2 < bk ? k2 : bk;
        }
        #pragma unroll
        for (int o = 1; o < 64; o <<= 1) {
            unsigned long long ok2 = __shfl_xor(bk, o);
            bk = ok2 < bk ? ok2 : bk;
        }
        if (lane == 0) atomicMin(&wbest[wv * 128 + p], bk);
    }
    __syncthreads();
    if (tid < 128) {
        unsigned long long k0 = wbest[tid];
        unsigned long long k1 = wbest[128 + tid];
        unsigned long long k2 = wbest[256 + tid];
        unsigned long long k3 = wbest[384 + tid];
        k0 = k1 < k0 ? k1 : k0;
        k2 = k3 < k2 ? k3 : k2;
        k0 = k2 < k0 ? k2 : k0;
        const int win = (int)(unsigned)(k0 & 0xFFFFFFFFULL);
        winner_s[tid] = win;
        out[IND_OFF + n0 + tid] = (float)win;
    }
    __syncthreads();
    // ---- finalize: gather winner rows, z_q writes, loss partial ----
    float lsum = 0.f;
    {
        const int px = tid >> 1, q = tid & 1;
        const int win = winner_s[px];
        const float4* wr = (const float4*)(ew + (size_t)win * EMB_ + q * 32);
        float4* xr = (float4*)(xs + px * 68 + q * 32);
        float4* zq4 = (float4*)(out + ZQ_OFF + (size_t)(n0 + px) * EMB_ + q * 32);
        #pragma unroll
        for (int i = 0; i < 8; i++) {
            float4 w4v = wr[i];
            float4 z4  = xr[i];
            float d0 = w4v.x - z4.x, d1 = w4v.y - z4.y;
            float d2 = w4v.z - z4.z, d3 = w4v.w - z4.w;
            lsum += d0*d0 + d1*d1 + d2*d2 + d3*d3;
            xr[i]  = w4v;
            zq4[i] = w4v;
        }
    }
    __syncthreads();
    // ---- transposed out writes ----
    {
        const int bI  = n0 >> 10;
        const int hw0 = n0 & 1023;
        #pragma unroll
        for (int hp = 0; hp < 2; hp++) {
            const int px = hp * 64 + lane;
            const float4* xr = (const float4*)(xs + px * 68 + wv * 16);
            float* ob = out + OUT_OFF + (size_t)bI * (EMB_ * 1024) + hw0 + px;
            #pragma unroll
            for (int i = 0; i < 4; i++) {
                float4 v = xr[i];
                const int e0 = wv * 16 + i * 4;
                ob[(size_t)(e0 + 0) * 1024] = v.x;
                ob[(size_t)(e0 + 1) * 1024] = v.y;
                ob[(size_t)(e0 + 2) * 1024] = v.z;
                ob[(size_t)(e0 + 3) * 1024] = v.w;
            }
        }
    }
    // ---- loss reduction + final scalar ----
    lred[tid] = lsum;
    __syncthreads();
    for (int o = 128; o > 0; o >>= 1) {
        if (tid < o) lred[tid] += lred[tid + o];
        __syncthreads();
    }
    if (tid == 0) {
        atomicAdd(lacc, lred[0]);
        __threadfence();
        int old = atomicAdd(done, 1);
        if (old == (int)gridDim.x - 1) {
            float tot = atomicAdd(lacc, 0.0f);
            out[LOSS_OFF] = 12.5f * (tot / 2097152.0f);
        }
    }
}

// ---------------------------------------------------------------------------
extern "C" void kernel_launch(void* const* d_in, const int* in_sizes, int n_in,
                              void* d_out, int out_size, void* d_ws, size_t ws_size,
                              hipStream_t stream)
{
    const float* z  = (const float*)d_in[0];
    const float* pw = (const float*)d_in[1];
    const float* pb = (const float*)d_in[2];
    const float* ew = (const float*)d_in[3];
    float* out = (float*)d_out;

    char* ws = (char*)d_ws;
    float4* W4   = (float4*)(ws);                      // 1,310,720
    float*  xsq  = (float*) (ws + 1310720);            //   131,072
    float*  wsq  = (float*) (ws + 1441792);            //    32,768
    float*  wsqp = (float*) (ws + 1474560);            //       128
    float*  lacc = (float*) (ws + 1474688);            //         4
    int*    done = (int*)   (ws + 1474692);            //         4

    float* z_e = out + ZQ_OFF;   // z_q_flat region doubles as z_e scratch

    hipLaunchKernelGGL(k_prep,  dim3(288), dim3(256), 0, stream,
                       z, pw, pb, ew, z_e, xsq, W4, wsq, wsqp, lacc, done);
    hipLaunchKernelGGL(k_fused, dim3(256), dim3(256), 0, stream,
                       W4, z_e, xsq, wsqp, wsq, ew, out, lacc, done);
}

// Round 7
// 206.820 us; speedup vs baseline: 1.4869x; 1.0090x over previous
//
#include <hip/hip_runtime.h>

// Problem constants
#define NPIX   32768      // B*H*W
#define NEMB_  8192
#define EMB_   64
#define CH_    128
#define NCHUNK 8          // 8 chunks x 32 tiles x 32 codes
#define CAPP   1024       // LDS pair-queue capacity (k_selfin)

// d_out layout (float elements)
#define OUT_OFF  0
#define ZQ_OFF   2097152
#define LOSS_OFF 4194304
#define IND_OFF  4194305

typedef _Float16 h8   __attribute__((ext_vector_type(8)));
typedef float    f16f __attribute__((ext_vector_type(16)));

// ---------------------------------------------------------------------------
// K1: codebook W-fragment pack + wsq + per-block max + init counters. grid 32.
// W' K-layout (80 slots): [0,64)=fp16(w); 64=wsq_hi, 65=wsq_lo; rest 0.
// Fragment: W4[(t*5+s)*64 + lane]: code m=32t+(lane&31), k=16s+8(lane>>5)+j
__global__ __launch_bounds__(256) void k_wpack(
    const float* __restrict__ ew, float4* __restrict__ W4,
    float* __restrict__ wsq, float* __restrict__ wsqp,
    float* __restrict__ lacc, int* __restrict__ done)
{
    const int tid = threadIdx.x;
    const int m   = blockIdx.x * 256 + tid;
    const float4* wr = (const float4*)(ew + (size_t)m * EMB_);
    float w[EMB_];
    float s = 0.f;
    #pragma unroll
    for (int i = 0; i < 16; i++) {
        float4 v = wr[i];
        w[4*i] = v.x; w[4*i+1] = v.y; w[4*i+2] = v.z; w[4*i+3] = v.w;
        s += v.x*v.x + v.y*v.y + v.z*v.z + v.w*v.w;
    }
    wsq[m] = s;
    float sh = (float)(_Float16)s;
    float sl = s - sh;
    const int t  = m >> 5;
    const int li = m & 31;
    #pragma unroll
    for (int s5 = 0; s5 < 4; s5++) {
        #pragma unroll
        for (int h = 0; h < 2; h++) {
            h8 hh;
            #pragma unroll
            for (int j = 0; j < 8; j++) hh[j] = (_Float16)w[s5 * 16 + h * 8 + j];
            W4[(size_t)(t * 5 + s5) * 64 + h * 32 + li] = __builtin_bit_cast(float4, hh);
        }
    }
    {
        h8 hh;
        #pragma unroll
        for (int j = 0; j < 8; j++) hh[j] = (_Float16)0.f;
        hh[0] = (_Float16)sh; hh[1] = (_Float16)sl;
        W4[(size_t)(t * 5 + 4) * 64 + 0 * 32 + li] = __builtin_bit_cast(float4, hh);
        #pragma unroll
        for (int j = 0; j < 8; j++) hh[j] = (_Float16)0.f;
        W4[(size_t)(t * 5 + 4) * 64 + 1 * 32 + li] = __builtin_bit_cast(float4, hh);
    }
    __shared__ float red[256];
    red[tid] = s;
    __syncthreads();
    for (int o = 128; o > 0; o >>= 1) {
        if (tid < o) red[tid] = fmaxf(red[tid], red[tid + o]);
        __syncthreads();
    }
    if (tid == 0) wsqp[blockIdx.x] = red[0];
    if (blockIdx.x == 0 && tid == 0) { *lacc = 0.f; *done = 0; }
}

// ---------------------------------------------------------------------------
// K2: projection. grid 512, block 256 = 64 px x 4 e-quarters (eq wave-uniform).
// wT staged transposed [c][e] so the inner loop reads 4 uniform b128/c.
__global__ __launch_bounds__(256) void k_proj(
    const float* __restrict__ z, const float* __restrict__ pw,
    const float* __restrict__ pb, float* __restrict__ z_e,
    float* __restrict__ xsq)
{
    __shared__ __align__(16) float wT[CH_ * EMB_];   // [c][e], 32 KB
    __shared__ float xp[4][64];
    const int tid = threadIdx.x;
    for (int i = tid; i < CH_ * EMB_; i += 256) {
        const int c = i >> 6, e = i & 63;
        wT[i] = pw[e * CH_ + c];                     // L2-hot scatter, 32 KB
    }
    __syncthreads();

    const int px = tid & 63;
    const int eq = tid >> 6;                         // wave-uniform
    const int n  = blockIdx.x * 64 + px;
    const int b  = n >> 10;
    const int hw = n & 1023;
    const float* zp = z + (size_t)b * (CH_ * 1024) + hw;

    float acc[16];
    #pragma unroll
    for (int j = 0; j < 16; j++) acc[j] = 0.f;

    #pragma unroll 4
    for (int c = 0; c < CH_; c++) {
        const float zv = zp[(size_t)c * 1024];       // coalesced across px
        const float4* wr = (const float4*)(wT + c * EMB_ + eq * 16);  // uniform
        float4 w0 = wr[0], w1 = wr[1], w2 = wr[2], w3 = wr[3];
        acc[0]  = fmaf(zv, w0.x, acc[0]);  acc[1]  = fmaf(zv, w0.y, acc[1]);
        acc[2]  = fmaf(zv, w0.z, acc[2]);  acc[3]  = fmaf(zv, w0.w, acc[3]);
        acc[4]  = fmaf(zv, w1.x, acc[4]);  acc[5]  = fmaf(zv, w1.y, acc[5]);
        acc[6]  = fmaf(zv, w1.z, acc[6]);  acc[7]  = fmaf(zv, w1.w, acc[7]);
        acc[8]  = fmaf(zv, w2.x, acc[8]);  acc[9]  = fmaf(zv, w2.y, acc[9]);
        acc[10] = fmaf(zv, w2.z, acc[10]); acc[11] = fmaf(zv, w2.w, acc[11]);
        acc[12] = fmaf(zv, w3.x, acc[12]); acc[13] = fmaf(zv, w3.y, acc[13]);
        acc[14] = fmaf(zv, w3.z, acc[14]); acc[15] = fmaf(zv, w3.w, acc[15]);
    }

    const float4* pb4 = (const float4*)(pb + eq * 16);
    float4 b0 = pb4[0], b1 = pb4[1], b2 = pb4[2], b3 = pb4[3];
    float bb[16] = {b0.x,b0.y,b0.z,b0.w, b1.x,b1.y,b1.z,b1.w,
                    b2.x,b2.y,b2.z,b2.w, b3.x,b3.y,b3.z,b3.w};
    float sq = 0.f;
    #pragma unroll
    for (int j = 0; j < 16; j++) { acc[j] += bb[j]; sq += acc[j] * acc[j]; }

    float4* zo = (float4*)(z_e + (size_t)n * EMB_ + eq * 16);
    zo[0] = make_float4(acc[0],  acc[1],  acc[2],  acc[3]);
    zo[1] = make_float4(acc[4],  acc[5],  acc[6],  acc[7]);
    zo[2] = make_float4(acc[8],  acc[9],  acc[10], acc[11]);
    zo[3] = make_float4(acc[12], acc[13], acc[14], acc[15]);
    xp[eq][px] = sq;
    __syncthreads();
    if (tid < 64)
        xsq[blockIdx.x * 64 + tid] = xp[0][tid] + xp[1][tid] + xp[2][tid] + xp[3][tid];
}

// ---------------------------------------------------------------------------
// K3: coarse MFMA pass. grid 512 (pxg = bIdx>>1, chunk-group = (bIdx&1)*4),
// wave = 128 px x 1 chunk (32 tiles). 2 blocks/CU = 2 waves/SIMD. Stats to
// global: per (chunk, px) top-3 tile maxima + top-2 tile indices.
__global__ __launch_bounds__(256, 2) void k_pass1(
    const float4* __restrict__ W4, const float* __restrict__ z_e,
    float* __restrict__ s1a, float* __restrict__ s2a, float* __restrict__ s3a,
    int* __restrict__ i1a, int* __restrict__ i2a)
{
    const int lane  = threadIdx.x & 63;
    const int wv    = threadIdx.x >> 6;
    const int pxg   = blockIdx.x >> 1;
    const int chunk = (blockIdx.x & 1) * 4 + wv;
    const int n0    = pxg * 128;
    const int hlf   = lane >> 5;

    // B-fragments (128 px per wave, lane-half = e-half)
    h8 bfr[4][5];
    #pragma unroll
    for (int j = 0; j < 4; j++) {
        const int px = n0 + j * 32 + (lane & 31);
        const float* zr = z_e + (size_t)px * EMB_ + (hlf << 3);
        #pragma unroll
        for (int s5 = 0; s5 < 4; s5++) {
            float4 u0 = *(const float4*)(zr + s5 * 16);
            float4 u1 = *(const float4*)(zr + s5 * 16 + 4);
            h8 hh;
            hh[0]=(_Float16)u0.x; hh[1]=(_Float16)u0.y; hh[2]=(_Float16)u0.z; hh[3]=(_Float16)u0.w;
            hh[4]=(_Float16)u1.x; hh[5]=(_Float16)u1.y; hh[6]=(_Float16)u1.z; hh[7]=(_Float16)u1.w;
            bfr[j][s5] = hh;
        }
        h8 hh;
        #pragma unroll
        for (int q = 0; q < 8; q++) hh[q] = (_Float16)0.f;
        if (hlf == 0) { hh[0] = (_Float16)-0.5f; hh[1] = (_Float16)-0.5f; }
        bfr[j][4] = hh;
    }

    const f16f kzero = {0,0,0,0,0,0,0,0,0,0,0,0,0,0,0,0};
    float s1[4], s2[4], s3[4];
    int   i1[4], i2[4];
    #pragma unroll
    for (int j = 0; j < 4; j++) { s1[j]=s2[j]=s3[j]=-3.0e38f; i1[j]=i2[j]=0; }

    const int tb = chunk * 32;
    float4 a4[5];
    {
        const float4* wp = W4 + (size_t)tb * 320 + lane;
        #pragma unroll
        for (int s = 0; s < 5; s++) a4[s] = wp[s * 64];
    }
    for (int tt = 0; tt < 32; tt++) {
        const int gt = tb + tt;
        const int tn = tb + (tt < 31 ? tt + 1 : tt);
        const float4* wn = W4 + (size_t)tn * 320 + lane;
        float4 nx[5];
        #pragma unroll
        for (int s = 0; s < 5; s++) nx[s] = wn[s * 64];

        f16f acc[4];
        #pragma unroll
        for (int j = 0; j < 4; j++)
            acc[j] = __builtin_amdgcn_mfma_f32_32x32x16_f16(
                __builtin_bit_cast(h8, a4[0]), bfr[j][0], kzero, 0, 0, 0);
        #pragma unroll
        for (int s = 1; s < 5; s++) {
            h8 a = __builtin_bit_cast(h8, a4[s]);
            #pragma unroll
            for (int j = 0; j < 4; j++)
                acc[j] = __builtin_amdgcn_mfma_f32_32x32x16_f16(a, bfr[j][s], acc[j], 0, 0, 0);
        }
        #pragma unroll
        for (int j = 0; j < 4; j++) {
            float t0 = fmaxf(fmaxf(acc[j][0],  acc[j][1]),  acc[j][2]);
            float t1 = fmaxf(fmaxf(acc[j][3],  acc[j][4]),  acc[j][5]);
            float t2 = fmaxf(fmaxf(acc[j][6],  acc[j][7]),  acc[j][8]);
            float t3 = fmaxf(fmaxf(acc[j][9],  acc[j][10]), acc[j][11]);
            float t4 = fmaxf(fmaxf(acc[j][12], acc[j][13]), acc[j][14]);
            float v  = fmaxf(fmaxf(fmaxf(t0, t1), fmaxf(t2, t3)),
                             fmaxf(t4, acc[j][15]));
            v = fmaxf(v, __shfl_xor(v, 32));          // full 32-row tile max
            bool c1 = v > s1[j];
            bool c2 = v > s2[j];
            int  cand = c1 ? i1[j] : gt;
            i2[j] = c2 ? cand : i2[j];
            s3[j] = fmaxf(fminf(s2[j], v), s3[j]);
            s3[j] = fminf(s3[j], fmaxf(s2[j], v));
            s2[j] = fmaxf(fminf(s1[j], v), fminf(s2[j], fmaxf(s1[j], v)));
            i1[j] = c1 ? gt : i1[j];
            s1[j] = fmaxf(s1[j], v);
        }
        #pragma unroll
        for (int s = 0; s < 5; s++) a4[s] = nx[s];
    }

    if (lane < 32) {
        #pragma unroll
        for (int j = 0; j < 4; j++) {
            const size_t o = (size_t)chunk * NPIX + n0 + j * 32 + lane;
            s1a[o] = s1[j]; s2a[o] = s2[j]; s3a[o] = s3[j];
            i1a[o] = i1[j]; i2a[o] = i2[j];
        }
    }
}

// ---------------------------------------------------------------------------
// ordered-float key: lexicographic (dist, index) min == np argmin semantics
__device__ __forceinline__ unsigned long long pack_key(float d, int m)
{
    unsigned fb = __float_as_uint(d);
    fb ^= ((int)fb < 0) ? 0xFFFFFFFFu : 0x80000000u;
    return ((unsigned long long)fb << 32) | (unsigned)m;
}

// exact fp32 distance key for code m against LDS row xr (broadcast reads)
__device__ __forceinline__ unsigned long long lane_key2(
    int m, const float* __restrict__ xr,
    const float* __restrict__ ew, const float* __restrict__ wsq)
{
    const float4* w4 = (const float4*)(ew + (size_t)m * EMB_);
    const float4* x4 = (const float4*)xr;
    float a0 = 0.f, a1 = 0.f;
    #pragma unroll
    for (int i = 0; i < 8; i++) {
        float4 wv = w4[2*i],   xv = x4[2*i];
        float4 wu = w4[2*i+1], xu = x4[2*i+1];
        a0 = fmaf(wv.x, xv.x, a0); a0 = fmaf(wv.y, xv.y, a0);
        a0 = fmaf(wv.z, xv.z, a0); a0 = fmaf(wv.w, xv.w, a0);
        a1 = fmaf(wu.x, xu.x, a1); a1 = fmaf(wu.y, xu.y, a1);
        a1 = fmaf(wu.z, xu.z, a1); a1 = fmaf(wu.w, xu.w, a1);
    }
    float d = fmaf(-2.f, a0 + a1, wsq[m]);
    return pack_key(d, m);
}

// ---------------------------------------------------------------------------
// K4: select + finalize. grid 512, block = 64 px. Stats from global ->
// certify -> parallel drain (lane = code) -> gather/writes/loss.
__global__ __launch_bounds__(256) void k_selfin(
    const float* __restrict__ s1a, const float* __restrict__ s2a,
    const float* __restrict__ s3a, const int* __restrict__ i1a,
    const int* __restrict__ i2a, const float* __restrict__ xsq,
    const float* __restrict__ wsqp, const float* __restrict__ wsq,
    const float* __restrict__ ew, const float* __restrict__ z_e,
    float* __restrict__ out, float* __restrict__ lacc, int* __restrict__ done)
{
    __shared__ __align__(16) float xs[64][68];       // z_e rows, later winners
    __shared__ float s1s[512];                       // [px][ch]
    __shared__ float thr_s[64];
    __shared__ int   pairs[CAPP];
    __shared__ unsigned long long wbest[4][64];
    __shared__ int   winner_s[64];
    __shared__ int   smask[64];
    __shared__ float lred[256];
    __shared__ int   npair_s;
    __shared__ float wm_s;

    const int tid  = threadIdx.x;
    const int wv   = tid >> 6;
    const int lane = tid & 63;
    const int n0   = blockIdx.x * 64;

    if (tid == 0) npair_s = 0;
    if (tid < 64) smask[tid] = 0;
    wbest[wv][lane] = ~0ULL;
    if (tid < 32) {
        float w = wsqp[tid];
        #pragma unroll
        for (int o = 16; o > 0; o >>= 1) w = fmaxf(w, __shfl_xor(w, o));
        if (tid == 0) wm_s = w;
    }
    // stage x (64 px x 64 floats), coalesced
    #pragma unroll
    for (int k = 0; k < 4; k++) {
        const int idx = k * 256 + tid;
        const int px = idx >> 4, i = idx & 15;
        float4 v = *(const float4*)(z_e + (size_t)(n0 + px) * EMB_ + i * 4);
        ((float4*)&xs[px][0])[i] = v;
    }
    // stats: 512 cells (8 ch x 64 px) over 256 threads, coalesced in px
    float cs1[2], cs2[2], cs3[2];
    int   ci1[2], ci2[2];
    #pragma unroll
    for (int k = 0; k < 2; k++) {
        const int cell = k * 256 + tid;
        const int ch = cell >> 6, px = cell & 63;
        const size_t o = (size_t)ch * NPIX + n0 + px;
        cs1[k] = s1a[o]; cs2[k] = s2a[o]; cs3[k] = s3a[o];
        ci1[k] = i1a[o]; ci2[k] = i2a[o];
        s1s[px * 8 + ch] = cs1[k];
    }
    __syncthreads();
    if (tid < 64) {
        float s1g = s1s[tid * 8];
        #pragma unroll
        for (int c = 1; c < 8; c++) s1g = fmaxf(s1g, s1s[tid * 8 + c]);
        float E = 0.00125f * sqrtf(xsq[n0 + tid] * wm_s) + 1e-5f * wm_s + 3e-4f;
        thr_s[tid] = s1g - 2.0f * E;
    }
    __syncthreads();
    // push candidate (px, tile) pairs
    #pragma unroll
    for (int k = 0; k < 2; k++) {
        const int cell = k * 256 + tid;
        const int ch = cell >> 6, px = cell & 63;
        const float th = thr_s[px];
        if (cs3[k] >= th) {
            int pos = atomicAdd(&npair_s, 32);
            if (pos + 32 <= CAPP) {
                for (int t = 0; t < 32; t++) pairs[pos + t] = (px << 8) | (ch * 32 + t);
            } else {
                for (int t = 0; t < 32; t++)
                    if (pos + t < CAPP) pairs[pos + t] = -1;
                smask[px] = 1;
            }
        } else {
            if (cs1[k] >= th) {
                int pos = atomicAdd(&npair_s, 1);
                if (pos < CAPP) pairs[pos] = (px << 8) | ci1[k]; else smask[px] = 1;
            }
            if (cs2[k] >= th) {
                int pos = atomicAdd(&npair_s, 1);
                if (pos < CAPP) pairs[pos] = (px << 8) | ci2[k]; else smask[px] = 1;
            }
        }
    }
    __syncthreads();
    const int np = min(npair_s, CAPP);

    // drain: 2 pairs per wave-batch, lane = code
    for (int i = wv * 2; i < np; i += 8) {
        const int pr = (lane < 32) ? pairs[i] : ((i + 1 < np) ? pairs[i + 1] : -1);
        const int p  = (pr >= 0) ? (pr >> 8) : 0;
        const bool ok = (pr >= 0) && !smask[p];
        unsigned long long key = ~0ULL;
        if (ok) {
            const int m = (pr & 255) * 32 + (lane & 31);
            key = lane_key2(m, &xs[p][0], ew, wsq);
        }
        #pragma unroll
        for (int o = 1; o < 32; o <<= 1) {
            unsigned long long ok2 = __shfl_xor(key, o);
            key = ok2 < key ? ok2 : key;
        }
        if ((lane & 31) == 0 && ok)
            atomicMin(&wbest[wv][p], key);
    }
    // overflow fallback: full codebook rescan (statistically never)
    for (int p = wv; p < 64; p += 4) {
        if (!smask[p]) continue;
        unsigned long long bk = ~0ULL;
        for (int it = 0; it < 128; it++) {
            const int m = (2 * it + (lane >> 5)) * 32 + (lane & 31);
            unsigned long long k2 = lane_key2(m, &xs[p][0], ew, wsq);
            bk = k2 < bk ? k2 : bk;
        }
        #pragma unroll
        for (int o = 1; o < 64; o <<= 1) {
            unsigned long long ok2 = __shfl_xor(bk, o);
            bk = ok2 < bk ? ok2 : bk;
        }
        if (lane == 0) atomicMin(&wbest[wv][p], bk);
    }
    __syncthreads();
    if (tid < 64) {
        unsigned long long k0 = wbest[0][tid];
        unsigned long long k1 = wbest[1][tid];
        unsigned long long k2 = wbest[2][tid];
        unsigned long long k3 = wbest[3][tid];
        k0 = k1 < k0 ? k1 : k0;
        k2 = k3 < k2 ? k3 : k2;
        k0 = k2 < k0 ? k2 : k0;
        const int win = (int)(unsigned)(k0 & 0xFFFFFFFFULL);
        winner_s[tid] = win;
        out[IND_OFF + n0 + tid] = (float)win;
    }
    __syncthreads();
    // gather winner rows, z_q writes, loss partial; overwrite xs
    float lsum = 0.f;
    {
        const int px = tid >> 2, q = tid & 3;
        const int win = winner_s[px];
        const float4* wr = (const float4*)(ew + (size_t)win * EMB_ + q * 16);
        float4* xr  = (float4*)&xs[px][q * 16];
        float4* zq4 = (float4*)(out + ZQ_OFF + (size_t)(n0 + px) * EMB_ + q * 16);
        #pragma unroll
        for (int i = 0; i < 4; i++) {
            float4 w4v = wr[i];
            float4 z4  = xr[i];
            float d0 = w4v.x - z4.x, d1 = w4v.y - z4.y;
            float d2 = w4v.z - z4.z, d3 = w4v.w - z4.w;
            lsum += d0*d0 + d1*d1 + d2*d2 + d3*d3;
            xr[i]  = w4v;
            zq4[i] = w4v;
        }
    }
    __syncthreads();
    // transposed out writes: px = lane, wave wv covers e in [wv*16, wv*16+16)
    {
        const int bI  = n0 >> 10;
        const int hw0 = n0 & 1023;
        float* ob = out + OUT_OFF + (size_t)bI * (EMB_ * 1024) + hw0 + lane;
        #pragma unroll
        for (int e = wv * 16; e < wv * 16 + 16; e++)
            ob[(size_t)e * 1024] = xs[lane][e];
    }
    // loss reduction + final scalar (last of 512 blocks)
    lred[tid] = lsum;
    __syncthreads();
    for (int o = 128; o > 0; o >>= 1) {
        if (tid < o) lred[tid] += lred[tid + o];
        __syncthreads();
    }
    if (tid == 0) {
        atomicAdd(lacc, lred[0]);
        __threadfence();
        int old = atomicAdd(done, 1);
        if (old == (int)gridDim.x - 1) {
            float tot = atomicAdd(lacc, 0.0f);
            out[LOSS_OFF] = 12.5f * (tot / 2097152.0f);
        }
    }
}

// ---------------------------------------------------------------------------
extern "C" void kernel_launch(void* const* d_in, const int* in_sizes, int n_in,
                              void* d_out, int out_size, void* d_ws, size_t ws_size,
                              hipStream_t stream)
{
    const float* z  = (const float*)d_in[0];
    const float* pw = (const float*)d_in[1];
    const float* pb = (const float*)d_in[2];
    const float* ew = (const float*)d_in[3];
    float* out = (float*)d_out;

    char* ws = (char*)d_ws;
    float4* W4   = (float4*)(ws);                      // 1,310,720
    float*  s1a  = (float*) (ws + 1310720);            // 1,048,576
    float*  s2a  = (float*) (ws + 2359296);            // 1,048,576
    float*  s3a  = (float*) (ws + 3407872);            // 1,048,576
    int*    i1a  = (int*)   (ws + 4456448);            // 1,048,576
    int*    i2a  = (int*)   (ws + 5505024);            // 1,048,576
    float*  xsq  = (float*) (ws + 6553600);            //   131,072
    float*  wsq  = (float*) (ws + 6684672);            //    32,768
    float*  wsqp = (float*) (ws + 6717440);            //       128
    float*  lacc = (float*) (ws + 6717568);            //         4
    int*    done = (int*)   (ws + 6717572);            //         4

    float* z_e = out + ZQ_OFF;   // z_q_flat region doubles as z_e scratch

    hipLaunchKernelGGL(k_wpack,  dim3(32),  dim3(256), 0, stream,
                       ew, W4, wsq, wsqp, lacc, done);
    hipLaunchKernelGGL(k_proj,   dim3(512), dim3(256), 0, stream,
                       z, pw, pb, z_e, xsq);
    hipLaunchKernelGGL(k_pass1,  dim3(512), dim3(256), 0, stream,
                       W4, z_e, s1a, s2a, s3a, i1a, i2a);
    hipLaunchKernelGGL(k_selfin, dim3(512), dim3(256), 0, stream,
                       s1a, s2a, s3a, i1a, i2a, xsq, wsqp, wsq, ew, z_e,
                       out, lacc, done);
}